// Round 14
// baseline (313.152 us; speedup 1.0000x reference)
//
#include <hip/hip_runtime.h>
#include <hip/hip_bf16.h>
#include <cstdint>
#include <cstddef>

// Shapes fixed: B=64, N=1024, D=512, S=16, 3 iterations.
// Algebra: logits = sn·W'·x^T, W' = scale·Wq^T·Wk   (k never materialized)
//          ax = attn·x;  upd@Wih^T = ax@(Wih·Wv)^T  (v never materialized)
// R14: R13 minus the ln+transpose fusion (ln_rows + xt split again —
//      fused version was LDS-latency bound at 82us vs ~50us split).

typedef __bf16 bf16x8 __attribute__((ext_vector_type(8)));
typedef float f32x4 __attribute__((ext_vector_type(4)));

__device__ __forceinline__ float bf2f(unsigned int u) {
  union { unsigned int i; float f; } v; v.i = u << 16; return v.f;
}
__device__ __forceinline__ unsigned short f2bf(float x) {
  __hip_bfloat16 h = __float2bfloat16(x);
  unsigned short u;
  __builtin_memcpy(&u, &h, 2);
  return u;
}

#define GLD16(gp, lp)                                                       \
  __builtin_amdgcn_global_load_lds(                                         \
      (const __attribute__((address_space(1))) void*)(gp),                  \
      (__attribute__((address_space(3))) void*)(lp), 16, 0, 0)

// ---------------- merged prep (segmented grid, 13064 blocks) ----------------

__global__ void wprep_k(const float* __restrict__ w1, const float* __restrict__ w2,
                        const float* __restrict__ wih, const float* __restrict__ whh,
                        const float* __restrict__ bih, const float* __restrict__ bhh,
                        const float* __restrict__ mu, const float* __restrict__ ls,
                        const float* __restrict__ noise,
                        const float* __restrict__ Wq, const float* __restrict__ Wk,
                        const float* __restrict__ Wv,
                        unsigned short* __restrict__ w1_bf, unsigned short* __restrict__ w2_bf,
                        unsigned short* __restrict__ wih_bf, unsigned short* __restrict__ wcat,
                        float* __restrict__ bcat, float* __restrict__ slots,
                        unsigned short* __restrict__ wqT, unsigned short* __restrict__ wkT,
                        unsigned short* __restrict__ wvT) {
  __shared__ float tt[32][33];
  int blk = blockIdx.x, t = threadIdx.x;
  if (blk < 1024) {
    int i = blk * 256 + t; w1_bf[i] = f2bf(w1[i]);
  } else if (blk < 2048) {
    int i = (blk - 1024) * 256 + t; w2_bf[i] = f2bf(w2[i]);
  } else if (blk < 5120) {
    int i = (blk - 2048) * 256 + t; wih_bf[i] = f2bf(wih[i]);
  } else if (blk < 7168) {
    int i = (blk - 5120) * 256 + t;
    int j = i >> 9, d = i & 511;
    wcat[(size_t)j * 1024 + 512 + d] = f2bf(whh[(size_t)j * 512 + d]);
  } else if (blk < 8192) {
    int i = (blk - 7168) * 256 + t;
    int j = i >> 9, d = i & 511;
    wcat[(size_t)(1536 + j) * 1024 + 512 + d] = f2bf(whh[(size_t)(1024 + j) * 512 + d]);
  } else if (blk < 10240) {
    int i = (blk - 8192) * 256 + t;
    if (i < 262144) {
      int j = i >> 9, d = i & 511;
      wcat[(size_t)(1536 + j) * 1024 + d] = 0;
    } else {
      int k = i - 262144;
      int j = k >> 9, d = k & 511;
      wcat[(size_t)(1024 + j) * 1024 + 512 + d] = 0;
    }
  } else if (blk < 10248) {
    int j = (blk - 10240) * 256 + t;
    float v;
    if (j < 1024)      v = bih[j] + bhh[j];
    else if (j < 1536) v = bih[j];
    else               v = bhh[j - 512];
    bcat[j] = v;
  } else if (blk < 12296) {
    int i = (blk - 10248) * 256 + t;
    int d = i & 511;
    slots[i] = mu[d] + expf(ls[d]) * noise[i];
  } else {
    int blk2 = blk - 12296;              // 768 transpose blocks
    int mat = blk2 >> 8, tile = blk2 & 255;
    const float* in = mat == 0 ? Wq : (mat == 1 ? Wk : Wv);
    unsigned short* out = mat == 0 ? wqT : (mat == 1 ? wkT : wvT);
    int c0 = (tile & 15) << 5, r0 = (tile >> 4) << 5;
    int tx = t & 31, ty = t >> 5;
    #pragma unroll
    for (int i = 0; i < 4; ++i)
      tt[ty + 8 * i][tx] = in[(size_t)(r0 + ty + 8 * i) * 512 + c0 + tx];
    __syncthreads();
    #pragma unroll
    for (int i = 0; i < 4; ++i)
      out[(size_t)(c0 + ty + 8 * i) * 512 + r0 + tx] = f2bf(tt[tx][ty + 8 * i]);
  }
}

// ---------------- layernorm inputs (wave per row, D=512) ----------------

__global__ __launch_bounds__(256) void ln_rows_k(
    const float* __restrict__ in, const float* __restrict__ g, const float* __restrict__ b,
    unsigned short* __restrict__ out, int rows) {
  int w = threadIdx.x >> 6, lane = threadIdx.x & 63;
  int row = (blockIdx.x << 2) + w;
  if (row >= rows) return;
  const float4* rp = reinterpret_cast<const float4*>(in + (size_t)row * 512);
  float4 v0 = rp[lane], v1 = rp[lane + 64];
  float s = v0.x + v0.y + v0.z + v0.w + v1.x + v1.y + v1.z + v1.w;
  float q = v0.x*v0.x + v0.y*v0.y + v0.z*v0.z + v0.w*v0.w
          + v1.x*v1.x + v1.y*v1.y + v1.z*v1.z + v1.w*v1.w;
  #pragma unroll
  for (int o = 32; o > 0; o >>= 1) { s += __shfl_xor(s, o); q += __shfl_xor(q, o); }
  float m = s * (1.0f / 512.0f);
  float rstd = rsqrtf(q * (1.0f / 512.0f) - m * m + 1e-8f);
  const float4* gp = reinterpret_cast<const float4*>(g);
  const float4* bp = reinterpret_cast<const float4*>(b);
  float4 g0 = gp[lane], g1 = gp[lane + 64];
  float4 b0 = bp[lane], b1 = bp[lane + 64];
  ushort4 o0, o1;
  o0.x = f2bf((v0.x - m) * rstd * g0.x + b0.x);
  o0.y = f2bf((v0.y - m) * rstd * g0.y + b0.y);
  o0.z = f2bf((v0.z - m) * rstd * g0.z + b0.z);
  o0.w = f2bf((v0.w - m) * rstd * g0.w + b0.w);
  o1.x = f2bf((v1.x - m) * rstd * g1.x + b1.x);
  o1.y = f2bf((v1.y - m) * rstd * g1.y + b1.y);
  o1.z = f2bf((v1.z - m) * rstd * g1.z + b1.z);
  o1.w = f2bf((v1.w - m) * rstd * g1.w + b1.w);
  ushort4* op = reinterpret_cast<ushort4*>(out + (size_t)row * 512);
  op[lane] = o0; op[lane + 64] = o1;
}

// ---------------- xT[b][e][n] = x_bf[b*1024+n][e]  (64x64 LDS tiles) ----------------
// grid (16 nt, 8 et, 64 b), block 256

__global__ __launch_bounds__(256) void xt_k(const unsigned short* __restrict__ x,
                                            unsigned short* __restrict__ xT) {
  __shared__ unsigned short t[64][68];
  int nt = blockIdx.x, et = blockIdx.y, b = blockIdx.z;
  int r = threadIdx.x >> 3, c8 = (threadIdx.x & 7) << 3;
  #pragma unroll
  for (int p = 0; p < 2; ++p) {
    int row = r + (p << 5);
    *reinterpret_cast<uint4*>(&t[row][c8]) = *reinterpret_cast<const uint4*>(
        x + ((size_t)(b << 10) + (nt << 6) + row) * 512 + (et << 6) + c8);
  }
  __syncthreads();
  #pragma unroll
  for (int p = 0; p < 2; ++p) {
    int erow = r + (p << 5);
    ushort4 a, bb;
    #pragma unroll
    for (int j = 0; j < 4; ++j) ((unsigned short*)&a)[j] = t[c8 + j][erow];
    #pragma unroll
    for (int j = 0; j < 4; ++j) ((unsigned short*)&bb)[j] = t[c8 + 4 + j][erow];
    unsigned short* o = xT + ((size_t)(b << 9) + (et << 6) + erow) * 1024 + (nt << 6) + c8;
    *reinterpret_cast<ushort4*>(o) = a;
    *reinterpret_cast<ushort4*>(o + 4) = bb;
  }
}

// GRU (fused-gates layout) + LN
__global__ __launch_bounds__(256) void gru_ln_k(
    const float* __restrict__ gates, const float* __restrict__ hp,
    const float* __restrict__ g, const float* __restrict__ b,
    float* __restrict__ sgru, unsigned short* __restrict__ lnm) {
  int w = threadIdx.x >> 6, lane = threadIdx.x & 63;
  int row = (blockIdx.x << 2) + w;
  size_t gb = (size_t)row * 2048 + (lane << 3);
  size_t hb = (size_t)row * 512 + (lane << 3);
  float rs[8], zs[8], in_[8], hn[8], hv[8], y[8];
  #pragma unroll
  for (int c = 0; c < 2; ++c) {
    *reinterpret_cast<float4*>(rs + 4*c)  = *reinterpret_cast<const float4*>(gates + gb + 4*c);
    *reinterpret_cast<float4*>(zs + 4*c)  = *reinterpret_cast<const float4*>(gates + gb + 512 + 4*c);
    *reinterpret_cast<float4*>(in_ + 4*c) = *reinterpret_cast<const float4*>(gates + gb + 1024 + 4*c);
    *reinterpret_cast<float4*>(hn + 4*c)  = *reinterpret_cast<const float4*>(gates + gb + 1536 + 4*c);
    *reinterpret_cast<float4*>(hv + 4*c)  = *reinterpret_cast<const float4*>(hp + hb + 4*c);
  }
  float s = 0.f, q = 0.f;
  #pragma unroll
  for (int j = 0; j < 8; ++j) {
    float r = 1.0f / (1.0f + expf(-rs[j]));
    float z = 1.0f / (1.0f + expf(-zs[j]));
    float n = tanhf(in_[j] + r * hn[j]);
    float h = (1.0f - z) * n + z * hv[j];
    y[j] = h; s += h; q += h * h;
  }
  #pragma unroll
  for (int o = 32; o > 0; o >>= 1) { s += __shfl_xor(s, o); q += __shfl_xor(q, o); }
  float m = s * (1.0f / 512.0f);
  float rstd = rsqrtf(q * (1.0f / 512.0f) - m * m + 1e-8f);
  const float* gg = g + (lane << 3);
  const float* bb = b + (lane << 3);
  #pragma unroll
  for (int c = 0; c < 2; ++c)
    *reinterpret_cast<float4*>(sgru + hb + 4*c) = *reinterpret_cast<const float4*>(y + 4*c);
  uint4 o4;
  unsigned int p[8];
  #pragma unroll
  for (int j = 0; j < 8; ++j) p[j] = f2bf((y[j] - m) * rstd * gg[j] + bb[j]);
  o4.x = p[0] | (p[1] << 16); o4.y = p[2] | (p[3] << 16);
  o4.z = p[4] | (p[5] << 16); o4.w = p[6] | (p[7] << 16);
  *reinterpret_cast<uint4*>(lnm + hb) = o4;
}

// ---------------- gemm_pre: 64 blocks = gemm_cat(48) + W'T gemm(16), 128x128, BK=64 ----------------

__global__ __launch_bounds__(256) void gemm_pre(
    const unsigned short* __restrict__ wih_bf, const unsigned short* __restrict__ wvT,
    const unsigned short* __restrict__ wkT, const unsigned short* __restrict__ wqT,
    unsigned short* __restrict__ wcat, unsigned short* __restrict__ wpt, float scale) {
  __shared__ unsigned short sA[2][8192];
  __shared__ unsigned short sB[2][8192];
  const int blk = blockIdx.x;
  const int lane = threadIdx.x & 63, w = threadIdx.x >> 6;

  const unsigned short *A, *W;
  unsigned short* C;
  int row0, col0, ldc;
  float sc;
  if (blk < 48) {
    A = wih_bf; W = wvT; C = wcat; ldc = 1024; sc = 1.0f;
    row0 = (blk >> 2) << 7; col0 = (blk & 3) << 7;
  } else {
    A = wkT; W = wqT; C = wpt; ldc = 512; sc = scale;
    int f = blk - 48;
    row0 = (f >> 2) << 7; col0 = (f & 3) << 7;
  }
  const int K = 512;

  const int wm = (w >> 1) << 6, wn = (w & 1) << 6;
  const int lrow = lane & 15, kt = (lane >> 4) << 3;
  const int sr8 = lane >> 3, sc8 = (lane & 7) << 3;

  f32x4 acc[4][4];
  #pragma unroll
  for (int m = 0; m < 4; ++m)
    #pragma unroll
    for (int n = 0; n < 4; ++n) acc[m][n] = f32x4{0.f, 0.f, 0.f, 0.f};

  auto stage = [&](int buf, int k0) {
    #pragma unroll
    for (int i = 0; i < 4; ++i) {
      int ii = (w << 2) + i;
      int r = (ii << 3) + sr8;
      GLD16(A + (size_t)(row0 + r) * K + k0 + sc8, &sA[buf][ii * 512]);
      GLD16(W + (size_t)(col0 + r) * K + k0 + sc8, &sB[buf][ii * 512]);
    }
  };

  stage(0, 0);
  int cur = 0;
  for (int t = 0; t < 8; ++t) {
    __syncthreads();
    if (t + 1 < 8) stage(cur ^ 1, (t + 1) << 6);
    #pragma unroll
    for (int kk = 0; kk < 2; ++kk) {
      bf16x8 af[4], bfv[4];
      #pragma unroll
      for (int m = 0; m < 4; ++m)
        af[m] = *reinterpret_cast<const bf16x8*>(&sA[cur][(wm + m * 16 + lrow) * 64 + (kk << 5) + kt]);
      #pragma unroll
      for (int n = 0; n < 4; ++n)
        bfv[n] = *reinterpret_cast<const bf16x8*>(&sB[cur][(wn + n * 16 + lrow) * 64 + (kk << 5) + kt]);
      #pragma unroll
      for (int m = 0; m < 4; ++m)
        #pragma unroll
        for (int n = 0; n < 4; ++n)
          acc[m][n] = __builtin_amdgcn_mfma_f32_16x16x32_bf16(af[m], bfv[n], acc[m][n], 0, 0, 0);
    }
    cur ^= 1;
  }

  const int rb = (lane >> 4) << 2;
  #pragma unroll
  for (int m = 0; m < 4; ++m) {
    #pragma unroll
    for (int n = 0; n < 4; ++n) {
      int col = col0 + wn + n * 16 + lrow;
      #pragma unroll
      for (int r = 0; r < 4; ++r) {
        int row = row0 + wm + m * 16 + rb + r;
        C[(size_t)row * ldc + col] = f2bf(acc[m][n][r] * sc);
      }
    }
  }
}

// ---------------- q2ln: LN(slots_b) in LDS, then q2 = sn @ W' tile (BK=64) ----------------

__global__ __launch_bounds__(256) void q2ln_k(
    const float* __restrict__ slots, const float* __restrict__ g, const float* __restrict__ b,
    const unsigned short* __restrict__ wpt, unsigned short* __restrict__ q2,
    unsigned short* __restrict__ A2) {
  __shared__ unsigned short s_sn[16 * 520];
  __shared__ unsigned short sB[2][8192];
  const int b_ = blockIdx.y, ct = blockIdx.x;
  const int lane = threadIdx.x & 63, w = threadIdx.x >> 6;
  const int lrow = lane & 15, kt = (lane >> 4) << 3;
  const int sr8 = lane >> 3, sc8 = (lane & 7) << 3;

  const float4* gp = reinterpret_cast<const float4*>(g);
  const float4* bp = reinterpret_cast<const float4*>(b);
  float4 g0 = gp[lane], g1 = gp[lane + 64];
  float4 b0 = bp[lane], b1 = bp[lane + 64];
  #pragma unroll
  for (int rr = 0; rr < 4; ++rr) {
    int r = w * 4 + rr;
    const float4* rp = reinterpret_cast<const float4*>(slots + (size_t)(b_ * 16 + r) * 512);
    float4 v0 = rp[lane], v1 = rp[lane + 64];
    float s = v0.x + v0.y + v0.z + v0.w + v1.x + v1.y + v1.z + v1.w;
    float q = v0.x*v0.x + v0.y*v0.y + v0.z*v0.z + v0.w*v0.w
            + v1.x*v1.x + v1.y*v1.y + v1.z*v1.z + v1.w*v1.w;
    #pragma unroll
    for (int o = 32; o > 0; o >>= 1) { s += __shfl_xor(s, o); q += __shfl_xor(q, o); }
    float m = s * (1.0f / 512.0f);
    float rstd = rsqrtf(q * (1.0f / 512.0f) - m * m + 1e-8f);
    ushort4 o0, o1;
    o0.x = f2bf((v0.x - m) * rstd * g0.x + b0.x);
    o0.y = f2bf((v0.y - m) * rstd * g0.y + b0.y);
    o0.z = f2bf((v0.z - m) * rstd * g0.z + b0.z);
    o0.w = f2bf((v0.w - m) * rstd * g0.w + b0.w);
    o1.x = f2bf((v1.x - m) * rstd * g1.x + b1.x);
    o1.y = f2bf((v1.y - m) * rstd * g1.y + b1.y);
    o1.z = f2bf((v1.z - m) * rstd * g1.z + b1.z);
    o1.w = f2bf((v1.w - m) * rstd * g1.w + b1.w);
    *reinterpret_cast<ushort4*>(&s_sn[r * 520 + lane * 4]) = o0;
    *reinterpret_cast<ushort4*>(&s_sn[r * 520 + 256 + lane * 4]) = o1;
    if (ct == 0) {
      ushort4 c0, c1;
      c0.x = f2bf(v0.x); c0.y = f2bf(v0.y); c0.z = f2bf(v0.z); c0.w = f2bf(v0.w);
      c1.x = f2bf(v1.x); c1.y = f2bf(v1.y); c1.z = f2bf(v1.z); c1.w = f2bf(v1.w);
      unsigned short* a2r = A2 + (size_t)(b_ * 16 + r) * 1024 + 512;
      *reinterpret_cast<ushort4*>(a2r + lane * 4) = c0;
      *reinterpret_cast<ushort4*>(a2r + 256 + lane * 4) = c1;
    }
  }

  const unsigned short* Bb = wpt + (size_t)(ct << 7) * 512;
  auto stage = [&](int buf, int k0) {
    #pragma unroll
    for (int i = 0; i < 4; ++i) {
      int ii = (w << 2) + i;
      GLD16(Bb + (size_t)((ii << 3) + sr8) * 512 + k0 + sc8, &sB[buf][ii * 512]);
    }
  };

  f32x4 acc[2];
  acc[0] = f32x4{0.f, 0.f, 0.f, 0.f};
  acc[1] = f32x4{0.f, 0.f, 0.f, 0.f};

  stage(0, 0);
  int cur = 0;
  for (int t = 0; t < 8; ++t) {
    __syncthreads();
    if (t + 1 < 8) stage(cur ^ 1, (t + 1) << 6);
    #pragma unroll
    for (int kk = 0; kk < 2; ++kk) {
      bf16x8 af = *reinterpret_cast<const bf16x8*>(&s_sn[lrow * 520 + (t << 6) + (kk << 5) + kt]);
      #pragma unroll
      for (int ni = 0; ni < 2; ++ni) {
        bf16x8 bfv = *reinterpret_cast<const bf16x8*>(
            &sB[cur][((w * 2 + ni) * 16 + lrow) * 64 + (kk << 5) + kt]);
        acc[ni] = __builtin_amdgcn_mfma_f32_16x16x32_bf16(af, bfv, acc[ni], 0, 0, 0);
      }
    }
    cur ^= 1;
  }

  const int rb = (lane >> 4) << 2;
  #pragma unroll
  for (int ni = 0; ni < 2; ++ni) {
    int col = (ct << 7) + (w * 2 + ni) * 16 + lrow;
    #pragma unroll
    for (int r = 0; r < 4; ++r) {
      int s = rb + r;
      q2[(size_t)((b_ << 4) + s) * 512 + col] = f2bf(acc[ni][r]);
    }
  }
}

// ---------------- logits + per-chunk softmax stats (bf16 out, BK=64) ----------------

__global__ __launch_bounds__(256) void logits_k(
    const unsigned short* __restrict__ q2, const unsigned short* __restrict__ x,
    unsigned short* __restrict__ out, float* __restrict__ lstats) {
  __shared__ unsigned short sA[2][1024];
  __shared__ unsigned short sB[2][8192];
  __shared__ float sstat[16][4][2];
  const int b = blockIdx.y, nt = blockIdx.x;
  const int lane = threadIdx.x & 63, w = threadIdx.x >> 6;
  const int lrow = lane & 15, kt = (lane >> 4) << 3;
  const int sr8 = lane >> 3, sc8 = (lane & 7) << 3;
  const unsigned short* Ab = q2 + ((size_t)b << 13);
  const unsigned short* Bb = x + (((size_t)(b << 10) + (nt << 7)) << 9);

  f32x4 acc[2];
  acc[0] = f32x4{0.f, 0.f, 0.f, 0.f};
  acc[1] = f32x4{0.f, 0.f, 0.f, 0.f};

  auto stage = [&](int buf, int k0) {
    #pragma unroll
    for (int i = 0; i < 4; ++i) {
      int ii = (w << 2) + i;
      GLD16(Bb + (size_t)((ii << 3) + sr8) * 512 + k0 + sc8, &sB[buf][ii * 512]);
    }
    if (w == 0) {
      #pragma unroll
      for (int i = 0; i < 2; ++i)
        GLD16(Ab + (size_t)((i << 3) + sr8) * 512 + k0 + sc8, &sA[buf][i * 512]);
    }
  };

  stage(0, 0);
  int cur = 0;
  for (int t = 0; t < 8; ++t) {
    __syncthreads();
    if (t + 1 < 8) stage(cur ^ 1, (t + 1) << 6);
    #pragma unroll
    for (int kk = 0; kk < 2; ++kk) {
      bf16x8 af = *reinterpret_cast<const bf16x8*>(&sA[cur][lrow * 64 + (kk << 5) + kt]);
      #pragma unroll
      for (int ni = 0; ni < 2; ++ni) {
        bf16x8 bfv = *reinterpret_cast<const bf16x8*>(
            &sB[cur][((w * 2 + ni) * 16 + lrow) * 64 + (kk << 5) + kt]);
        acc[ni] = __builtin_amdgcn_mfma_f32_16x16x32_bf16(af, bfv, acc[ni], 0, 0, 0);
      }
    }
    cur ^= 1;
  }

  const int rb = (lane >> 4) << 2;
  unsigned short lv[2][4];
  #pragma unroll
  for (int ni = 0; ni < 2; ++ni) {
    int n = (nt << 7) + (w * 2 + ni) * 16 + lrow;
    #pragma unroll
    for (int r = 0; r < 4; ++r) {
      unsigned short u = f2bf(acc[ni][r]);
      lv[ni][r] = u;
      out[(size_t)((b << 4) + rb + r) * 1024 + n] = u;
    }
  }
  #pragma unroll
  for (int r = 0; r < 4; ++r) {
    float v0 = bf2f(lv[0][r]), v1 = bf2f(lv[1][r]);
    float m = fmaxf(v0, v1);
    #pragma unroll
    for (int o = 1; o < 16; o <<= 1) m = fmaxf(m, __shfl_xor(m, o));
    float l = __expf(v0 - m) + __expf(v1 - m);
    #pragma unroll
    for (int o = 1; o < 16; o <<= 1) l += __shfl_xor(l, o);
    if (lrow == 0) { sstat[rb + r][w][0] = m; sstat[rb + r][w][1] = l; }
  }
  __syncthreads();
  if (threadIdx.x < 16) {
    int s = threadIdx.x;
    float m = sstat[s][0][0];
    #pragma unroll
    for (int c = 1; c < 4; ++c) m = fmaxf(m, sstat[s][c][0]);
    float l = 0.f;
    #pragma unroll
    for (int c = 0; c < 4; ++c) l += sstat[s][c][1] * __expf(sstat[s][c][0] - m);
    float* lp = lstats + (((size_t)(b << 4) + s) * 8 + nt) * 2;
    lp[0] = m; lp[1] = l;
  }
}

// ---------------- pv_sm: stats-combine + colnorm (LDS attn) + ax MFMA vs xT ----------------

__global__ __launch_bounds__(256) void pv_sm_k(
    const unsigned short* __restrict__ logits, const float* __restrict__ lstats,
    const unsigned short* __restrict__ xT, unsigned short* __restrict__ A2) {
  __shared__ float s_mi[16][2];
  __shared__ unsigned short s_at[16 * 1032];
  __shared__ unsigned short sA[2][8192];
  const int b_ = blockIdx.y, et = blockIdx.x;
  const int lane = threadIdx.x & 63, w = threadIdx.x >> 6;
  const int lrow = lane & 15, kt = (lane >> 4) << 3;
  const int sr8 = lane >> 3, sc8 = (lane & 7) << 3;
  const unsigned short* lg = logits + ((size_t)b_ << 14);

  if (threadIdx.x < 16) {
    int s = threadIdx.x;
    const float* lp = lstats + (((size_t)(b_ << 4) + s) * 8) * 2;
    float m = lp[0];
    #pragma unroll
    for (int c = 1; c < 8; ++c) m = fmaxf(m, lp[c * 2]);
    float l = 0.f;
    #pragma unroll
    for (int c = 0; c < 8; ++c) l += lp[c * 2 + 1] * __expf(lp[c * 2] - m);
    s_mi[s][0] = m; s_mi[s][1] = 1.0f / l;
  }
  __syncthreads();

  #pragma unroll
  for (int j = 0; j < 4; ++j) {
    int c = threadIdx.x + (j << 8);
    float e[16];
    float cs = 0.f;
    #pragma unroll
    for (int s = 0; s < 16; ++s) {
      e[s] = __expf(bf2f(lg[(size_t)s * 1024 + c]) - s_mi[s][0]) * s_mi[s][1];
      cs += e[s];
    }
    float rv = 1.0f / (cs + 1e-8f);
    #pragma unroll
    for (int s = 0; s < 16; ++s) s_at[s * 1032 + c] = f2bf(e[s] * rv);
  }

  const unsigned short* Ab = xT + ((size_t)b_ << 19) + (size_t)(et << 7) * 1024;
  auto stage = [&](int buf, int k0) {
    #pragma unroll
    for (int i = 0; i < 4; ++i) {
      int ii = (w << 2) + i;
      GLD16(Ab + (size_t)((ii << 3) + sr8) * 1024 + k0 + sc8, &sA[buf][ii * 512]);
    }
  };

  f32x4 acc[2];
  acc[0] = f32x4{0.f, 0.f, 0.f, 0.f};
  acc[1] = f32x4{0.f, 0.f, 0.f, 0.f};

  stage(0, 0);
  int cur = 0;
  for (int t = 0; t < 16; ++t) {
    __syncthreads();
    if (t + 1 < 16) stage(cur ^ 1, (t + 1) << 6);
    #pragma unroll
    for (int kk = 0; kk < 2; ++kk) {
      bf16x8 bfv = *reinterpret_cast<const bf16x8*>(&s_at[lrow * 1032 + (t << 6) + (kk << 5) + kt]);
      #pragma unroll
      for (int mi = 0; mi < 2; ++mi) {
        bf16x8 af = *reinterpret_cast<const bf16x8*>(
            &sA[cur][((w * 2 + mi) * 16 + lrow) * 64 + (kk << 5) + kt]);
        acc[mi] = __builtin_amdgcn_mfma_f32_16x16x32_bf16(af, bfv, acc[mi], 0, 0, 0);
      }
    }
    cur ^= 1;
  }

  const int rb = (lane >> 4) << 2;
  const int s = lrow;
  #pragma unroll
  for (int mi = 0; mi < 2; ++mi) {
    int e0 = (et << 7) + (w * 2 + mi) * 16 + rb;
    ushort4 o;
    o.x = f2bf(acc[mi][0]); o.y = f2bf(acc[mi][1]);
    o.z = f2bf(acc[mi][2]); o.w = f2bf(acc[mi][3]);
    *reinterpret_cast<ushort4*>(&A2[(size_t)((b_ << 4) + s) * 1024 + e0]) = o;
  }
}

// ---------------- MFMA GEMM 64x64 (slot-sized GEMMs, BK=64) ----------------
// GATES=1: N=2048 gates GEMM; cols [1024,1536) use K=[0,512), [1536,2048) K=[512,1024)

template<int BIAS, int RELU, int ADDSRC, int OUTBF16, int GATES>
__global__ __launch_bounds__(256) void gemm_sm(
    const unsigned short* __restrict__ A, const unsigned short* __restrict__ W,
    const float* __restrict__ bias, const float* __restrict__ addsrc,
    void* __restrict__ Cout, int M, int N, int K) {
  __shared__ unsigned short sA[2][4096];
  __shared__ unsigned short sB[2][4096];
  const int tid = threadIdx.x;
  const int lane = tid & 63, w = tid >> 6;

  int nwg = gridDim.x * gridDim.y;
  int flat = blockIdx.y * gridDim.x + blockIdx.x;
  if ((nwg & 7) == 0) { int c = nwg >> 3; flat = (flat & 7) * c + (flat >> 3); }
  const int row0 = (flat / gridDim.x) << 6;
  const int col0 = (flat % gridDim.x) << 6;

  int kb = 0, ke = K;
  if (GATES) {
    if (col0 >= 1536)      { kb = 512; ke = 1024; }
    else if (col0 >= 1024) { kb = 0;   ke = 512;  }
  }

  const int lrow = lane & 15, kt = (lane >> 4) << 3;
  const int sr8 = lane >> 3, sc8 = (lane & 7) << 3;

  f32x4 acc[4];
  #pragma unroll
  for (int m = 0; m < 4; ++m) acc[m] = f32x4{0.f, 0.f, 0.f, 0.f};

  auto stage = [&](int buf, int k0) {
    #pragma unroll
    for (int i = 0; i < 2; ++i) {
      int ii = (w << 1) + i;
      int r = (ii << 3) + sr8;
      GLD16(A + (size_t)(row0 + r) * K + k0 + sc8, &sA[buf][ii * 512]);
      GLD16(W + (size_t)(col0 + r) * K + k0 + sc8, &sB[buf][ii * 512]);
    }
  };

  stage(0, kb);
  const int nt = (ke - kb) >> 6;
  int cur = 0;
  for (int t = 0; t < nt; ++t) {
    __syncthreads();
    if (t + 1 < nt) stage(cur ^ 1, kb + ((t + 1) << 6));
    #pragma unroll
    for (int kk = 0; kk < 2; ++kk) {
      bf16x8 bfv = *reinterpret_cast<const bf16x8*>(
          &sB[cur][((w << 4) + lrow) * 64 + (kk << 5) + kt]);
      #pragma unroll
      for (int m = 0; m < 4; ++m) {
        bf16x8 af = *reinterpret_cast<const bf16x8*>(
            &sA[cur][(m * 16 + lrow) * 64 + (kk << 5) + kt]);
        acc[m] = __builtin_amdgcn_mfma_f32_16x16x32_bf16(af, bfv, acc[m], 0, 0, 0);
      }
    }
    cur ^= 1;
  }

  const int rb = (lane >> 4) << 2;
  const int col = col0 + (w << 4) + lrow;
  float bv = BIAS ? bias[col] : 0.0f;
  #pragma unroll
  for (int m = 0; m < 4; ++m) {
    #pragma unroll
    for (int r = 0; r < 4; ++r) {
      int row = row0 + m * 16 + rb + r;
      float v = acc[m][r] + bv;
      if (ADDSRC) v += addsrc[(size_t)row * N + col];
      if (RELU) v = fmaxf(v, 0.0f);
      if (OUTBF16) ((unsigned short*)Cout)[(size_t)row * N + col] = f2bf(v);
      else ((float*)Cout)[(size_t)row * N + col] = v;
    }
  }
}

// ---------------- host launch ----------------

extern "C" void kernel_launch(void* const* d_in, const int* in_sizes, int n_in,
                              void* d_out, int out_size, void* d_ws, size_t ws_size,
                              hipStream_t stream) {
  const float* inputs  = (const float*)d_in[0];
  const float* noise   = (const float*)d_in[1];
  const float* slot_mu = (const float*)d_in[2];
  const float* slot_ls = (const float*)d_in[3];
  const float* ln_in_g = (const float*)d_in[4];
  const float* ln_in_b = (const float*)d_in[5];
  const float* ln_s_g  = (const float*)d_in[6];
  const float* ln_s_b  = (const float*)d_in[7];
  const float* ln_m_g  = (const float*)d_in[8];
  const float* ln_m_b  = (const float*)d_in[9];
  const float* Wq   = (const float*)d_in[10];
  const float* Wk   = (const float*)d_in[11];
  const float* Wv   = (const float*)d_in[12];
  const float* w_ih = (const float*)d_in[13];
  const float* w_hh = (const float*)d_in[14];
  const float* b_ih = (const float*)d_in[15];
  const float* b_hh = (const float*)d_in[16];
  const float* w1   = (const float*)d_in[17];
  const float* b1   = (const float*)d_in[18];
  const float* w2   = (const float*)d_in[19];
  const float* b2   = (const float*)d_in[20];

  const int BN = 65536, BS = 1024;

  uintptr_t base = (uintptr_t)d_ws;
  auto alloc = [&](size_t bytes) {
    void* p = (void*)base;
    base += (bytes + 255) & ~(size_t)255;
    return p;
  };
  unsigned short* x_bf    = (unsigned short*)alloc((size_t)BN * 512 * 2);
  unsigned short* xT      = (unsigned short*)alloc((size_t)64 * 512 * 1024 * 2);
  unsigned short* wqT     = (unsigned short*)alloc(512 * 512 * 2);
  unsigned short* wkT     = (unsigned short*)alloc(512 * 512 * 2);
  unsigned short* wvT     = (unsigned short*)alloc(512 * 512 * 2);
  unsigned short* wpt     = (unsigned short*)alloc(512 * 512 * 2);
  unsigned short* wih_bf  = (unsigned short*)alloc((size_t)1536 * 512 * 2);
  unsigned short* wcat_bf = (unsigned short*)alloc((size_t)2048 * 1024 * 2);
  float*          bcat    = (float*)alloc(2048 * 4);
  unsigned short* w1_bf   = (unsigned short*)alloc(512 * 512 * 2);
  unsigned short* w2_bf   = (unsigned short*)alloc(512 * 512 * 2);
  float*          slots   = (float*)alloc((size_t)BS * 512 * 4);
  unsigned short* A2      = (unsigned short*)alloc((size_t)BS * 1024 * 2);
  unsigned short* q2_bf   = (unsigned short*)alloc((size_t)BS * 512 * 2);
  unsigned short* logits  = (unsigned short*)alloc((size_t)64 * 16 * 1024 * 2);
  float*          lstats  = (float*)alloc((size_t)64 * 16 * 8 * 2 * 4);
  float*          gates   = (float*)alloc((size_t)BS * 2048 * 4);
  float*          sgru    = (float*)alloc((size_t)BS * 512 * 4);
  unsigned short* lnm_bf  = (unsigned short*)alloc((size_t)BS * 512 * 2);
  unsigned short* h_bf    = (unsigned short*)alloc((size_t)BS * 512 * 2);
  (void)ws_size; (void)n_in; (void)in_sizes; (void)out_size;

  const float scale = 0.044194173824159216f;  // 512^-0.5

  // prologue (4 dispatches)
  wprep_k<<<13064, 256, 0, stream>>>(w1, w2, w_ih, w_hh, b_ih, b_hh,
                                     slot_mu, slot_ls, noise, Wq, Wk, Wv,
                                     w1_bf, w2_bf, wih_bf, wcat_bf, bcat, slots,
                                     wqT, wkT, wvT);
  gemm_pre<<<64, 256, 0, stream>>>(wih_bf, wvT, wkT, wqT, wcat_bf, wpt, scale);
  ln_rows_k<<<16384, 256, 0, stream>>>(inputs, ln_in_g, ln_in_b, x_bf, BN);
  xt_k<<<dim3(16, 8, 64), 256, 0, stream>>>(x_bf, xT);

  for (int it = 0; it < 3; ++it) {
    q2ln_k<<<dim3(4, 64), 256, 0, stream>>>(slots, ln_s_g, ln_s_b, wpt, q2_bf, A2);
    logits_k<<<dim3(8, 64), 256, 0, stream>>>(q2_bf, x_bf, logits, lstats);
    pv_sm_k<<<dim3(4, 64), 256, 0, stream>>>(logits, lstats, xT, A2);
    gemm_sm<1,0,0,0,1><<<dim3(32, 16), 256, 0, stream>>>(
        A2, wcat_bf, bcat, nullptr, gates, BS, 2048, 1024);
    gru_ln_k<<<256, 256, 0, stream>>>(gates, slots, ln_m_g, ln_m_b, sgru, lnm_bf);
    gemm_sm<1,1,0,1,0><<<dim3(8, 16), 256, 0, stream>>>(
        lnm_bf, w1_bf, b1, nullptr, h_bf, BS, 512, 512);
    float* slots_out = (it == 2) ? (float*)d_out : slots;
    gemm_sm<1,0,1,0,0><<<dim3(8, 16), 256, 0, stream>>>(
        h_bf, w2_bf, b2, sgru, slots_out, BS, 512, 512);
  }
}

// Round 15
// 309.007 us; speedup vs baseline: 1.0134x; 1.0134x over previous
//
#include <hip/hip_runtime.h>
#include <hip/hip_bf16.h>
#include <cstdint>
#include <cstddef>

// Shapes fixed: B=64, N=1024, D=512, S=16, 3 iterations.
// Algebra: logits = sn·W'·x^T, W' = scale·Wq^T·Wk   (k never materialized)
//          ax = attn·x;  upd@Wih^T = ax@(Wih·Wv)^T  (v never materialized)
// R15: R14 + fused ln_xt with XOR-swizzled LDS transpose (conflict-free;
//      R13's fused version lost 30us to 4-way bank conflicts).

typedef __bf16 bf16x8 __attribute__((ext_vector_type(8)));
typedef float f32x4 __attribute__((ext_vector_type(4)));

__device__ __forceinline__ float bf2f(unsigned int u) {
  union { unsigned int i; float f; } v; v.i = u << 16; return v.f;
}
__device__ __forceinline__ unsigned short f2bf(float x) {
  __hip_bfloat16 h = __float2bfloat16(x);
  unsigned short u;
  __builtin_memcpy(&u, &h, 2);
  return u;
}

#define GLD16(gp, lp)                                                       \
  __builtin_amdgcn_global_load_lds(                                         \
      (const __attribute__((address_space(1))) void*)(gp),                  \
      (__attribute__((address_space(3))) void*)(lp), 16, 0, 0)

// ---------------- merged prep (segmented grid, 13064 blocks) ----------------

__global__ void wprep_k(const float* __restrict__ w1, const float* __restrict__ w2,
                        const float* __restrict__ wih, const float* __restrict__ whh,
                        const float* __restrict__ bih, const float* __restrict__ bhh,
                        const float* __restrict__ mu, const float* __restrict__ ls,
                        const float* __restrict__ noise,
                        const float* __restrict__ Wq, const float* __restrict__ Wk,
                        const float* __restrict__ Wv,
                        unsigned short* __restrict__ w1_bf, unsigned short* __restrict__ w2_bf,
                        unsigned short* __restrict__ wih_bf, unsigned short* __restrict__ wcat,
                        float* __restrict__ bcat, float* __restrict__ slots,
                        unsigned short* __restrict__ wqT, unsigned short* __restrict__ wkT,
                        unsigned short* __restrict__ wvT) {
  __shared__ float tt[32][33];
  int blk = blockIdx.x, t = threadIdx.x;
  if (blk < 1024) {
    int i = blk * 256 + t; w1_bf[i] = f2bf(w1[i]);
  } else if (blk < 2048) {
    int i = (blk - 1024) * 256 + t; w2_bf[i] = f2bf(w2[i]);
  } else if (blk < 5120) {
    int i = (blk - 2048) * 256 + t; wih_bf[i] = f2bf(wih[i]);
  } else if (blk < 7168) {
    int i = (blk - 5120) * 256 + t;
    int j = i >> 9, d = i & 511;
    wcat[(size_t)j * 1024 + 512 + d] = f2bf(whh[(size_t)j * 512 + d]);
  } else if (blk < 8192) {
    int i = (blk - 7168) * 256 + t;
    int j = i >> 9, d = i & 511;
    wcat[(size_t)(1536 + j) * 1024 + 512 + d] = f2bf(whh[(size_t)(1024 + j) * 512 + d]);
  } else if (blk < 10240) {
    int i = (blk - 8192) * 256 + t;
    if (i < 262144) {
      int j = i >> 9, d = i & 511;
      wcat[(size_t)(1536 + j) * 1024 + d] = 0;
    } else {
      int k = i - 262144;
      int j = k >> 9, d = k & 511;
      wcat[(size_t)(1024 + j) * 1024 + 512 + d] = 0;
    }
  } else if (blk < 10248) {
    int j = (blk - 10240) * 256 + t;
    float v;
    if (j < 1024)      v = bih[j] + bhh[j];
    else if (j < 1536) v = bih[j];
    else               v = bhh[j - 512];
    bcat[j] = v;
  } else if (blk < 12296) {
    int i = (blk - 10248) * 256 + t;
    int d = i & 511;
    slots[i] = mu[d] + expf(ls[d]) * noise[i];
  } else {
    int blk2 = blk - 12296;              // 768 transpose blocks
    int mat = blk2 >> 8, tile = blk2 & 255;
    const float* in = mat == 0 ? Wq : (mat == 1 ? Wk : Wv);
    unsigned short* out = mat == 0 ? wqT : (mat == 1 ? wkT : wvT);
    int c0 = (tile & 15) << 5, r0 = (tile >> 4) << 5;
    int tx = t & 31, ty = t >> 5;
    #pragma unroll
    for (int i = 0; i < 4; ++i)
      tt[ty + 8 * i][tx] = in[(size_t)(r0 + ty + 8 * i) * 512 + c0 + tx];
    __syncthreads();
    #pragma unroll
    for (int i = 0; i < 4; ++i)
      out[(size_t)(c0 + ty + 8 * i) * 512 + r0 + tx] = f2bf(tt[tx][ty + 8 * i]);
  }
}

// ---------------- ln_xt: LN(inputs) -> x_bf AND xT, XOR-swizzled transpose ----------------
// grid 2048 blocks (32 rows each, never straddling a batch), LDS 33KB -> 4 blocks/CU.
// LDS store col: c ^ (((r>>3)&3)<<3)  -> transpose reads are bank-conflict-free.

__global__ __launch_bounds__(256) void ln_xt_k(
    const float* __restrict__ in, const float* __restrict__ g, const float* __restrict__ b,
    unsigned short* __restrict__ x_bf, unsigned short* __restrict__ xT) {
  __shared__ unsigned short tbuf[32 * 520];
  const int row0 = blockIdx.x << 5;
  const int bb_ = row0 >> 10;
  const int n0 = row0 & 1023;
  const int w = threadIdx.x >> 6, lane = threadIdx.x & 63;

  const float4* gp = reinterpret_cast<const float4*>(g);
  const float4* bp = reinterpret_cast<const float4*>(b);
  float4 g0 = gp[lane], g1 = gp[lane + 64];
  float4 b0 = bp[lane], b1 = bp[lane + 64];

  #pragma unroll
  for (int i = 0; i < 8; ++i) {
    int r = (w << 3) + i;
    int row = row0 + r;
    const float4* rp = reinterpret_cast<const float4*>(in + (size_t)row * 512);
    float4 v0 = rp[lane], v1 = rp[lane + 64];
    float s = v0.x + v0.y + v0.z + v0.w + v1.x + v1.y + v1.z + v1.w;
    float q = v0.x*v0.x + v0.y*v0.y + v0.z*v0.z + v0.w*v0.w
            + v1.x*v1.x + v1.y*v1.y + v1.z*v1.z + v1.w*v1.w;
    #pragma unroll
    for (int o = 32; o > 0; o >>= 1) { s += __shfl_xor(s, o); q += __shfl_xor(q, o); }
    float m = s * (1.0f / 512.0f);
    float rstd = rsqrtf(q * (1.0f / 512.0f) - m * m + 1e-8f);
    ushort4 o0, o1;
    o0.x = f2bf((v0.x - m) * rstd * g0.x + b0.x);
    o0.y = f2bf((v0.y - m) * rstd * g0.y + b0.y);
    o0.z = f2bf((v0.z - m) * rstd * g0.z + b0.z);
    o0.w = f2bf((v0.w - m) * rstd * g0.w + b0.w);
    o1.x = f2bf((v1.x - m) * rstd * g1.x + b1.x);
    o1.y = f2bf((v1.y - m) * rstd * g1.y + b1.y);
    o1.z = f2bf((v1.z - m) * rstd * g1.z + b1.z);
    o1.w = f2bf((v1.w - m) * rstd * g1.w + b1.w);
    ushort4* op = reinterpret_cast<ushort4*>(x_bf + (size_t)row * 512);
    op[lane] = o0; op[lane + 64] = o1;
    const int key = ((r >> 3) & 3) << 3;
    *reinterpret_cast<ushort4*>(&tbuf[r * 520 + ((lane * 4) ^ key)]) = o0;
    *reinterpret_cast<ushort4*>(&tbuf[r * 520 + ((256 + lane * 4) ^ key)]) = o1;
  }
  __syncthreads();

  // transpose: thread (e_lo = tid>>2, n8 = (tid&3)*8) reads 8 rows of column e
  const int e_lo = threadIdx.x >> 2;
  const int n8 = (threadIdx.x & 3) << 3;
  const int key = ((n8 >> 3) & 3) << 3;   // constant over the 8 rows n8..n8+7
  #pragma unroll
  for (int et = 0; et < 8; ++et) {
    int e = (et << 6) + e_lo;
    int es = e ^ key;
    ushort4 a, c;
    #pragma unroll
    for (int j = 0; j < 4; ++j) ((unsigned short*)&a)[j] = tbuf[(n8 + j) * 520 + es];
    #pragma unroll
    for (int j = 0; j < 4; ++j) ((unsigned short*)&c)[j] = tbuf[(n8 + 4 + j) * 520 + es];
    unsigned short* o = xT + ((size_t)(bb_ << 9) + e) * 1024 + n0 + n8;
    *reinterpret_cast<ushort4*>(o) = a;
    *reinterpret_cast<ushort4*>(o + 4) = c;
  }
}

// GRU (fused-gates layout) + LN
__global__ __launch_bounds__(256) void gru_ln_k(
    const float* __restrict__ gates, const float* __restrict__ hp,
    const float* __restrict__ g, const float* __restrict__ b,
    float* __restrict__ sgru, unsigned short* __restrict__ lnm) {
  int w = threadIdx.x >> 6, lane = threadIdx.x & 63;
  int row = (blockIdx.x << 2) + w;
  size_t gb = (size_t)row * 2048 + (lane << 3);
  size_t hb = (size_t)row * 512 + (lane << 3);
  float rs[8], zs[8], in_[8], hn[8], hv[8], y[8];
  #pragma unroll
  for (int c = 0; c < 2; ++c) {
    *reinterpret_cast<float4*>(rs + 4*c)  = *reinterpret_cast<const float4*>(gates + gb + 4*c);
    *reinterpret_cast<float4*>(zs + 4*c)  = *reinterpret_cast<const float4*>(gates + gb + 512 + 4*c);
    *reinterpret_cast<float4*>(in_ + 4*c) = *reinterpret_cast<const float4*>(gates + gb + 1024 + 4*c);
    *reinterpret_cast<float4*>(hn + 4*c)  = *reinterpret_cast<const float4*>(gates + gb + 1536 + 4*c);
    *reinterpret_cast<float4*>(hv + 4*c)  = *reinterpret_cast<const float4*>(hp + hb + 4*c);
  }
  float s = 0.f, q = 0.f;
  #pragma unroll
  for (int j = 0; j < 8; ++j) {
    float r = 1.0f / (1.0f + expf(-rs[j]));
    float z = 1.0f / (1.0f + expf(-zs[j]));
    float n = tanhf(in_[j] + r * hn[j]);
    float h = (1.0f - z) * n + z * hv[j];
    y[j] = h; s += h; q += h * h;
  }
  #pragma unroll
  for (int o = 32; o > 0; o >>= 1) { s += __shfl_xor(s, o); q += __shfl_xor(q, o); }
  float m = s * (1.0f / 512.0f);
  float rstd = rsqrtf(q * (1.0f / 512.0f) - m * m + 1e-8f);
  const float* gg = g + (lane << 3);
  const float* bb = b + (lane << 3);
  #pragma unroll
  for (int c = 0; c < 2; ++c)
    *reinterpret_cast<float4*>(sgru + hb + 4*c) = *reinterpret_cast<const float4*>(y + 4*c);
  uint4 o4;
  unsigned int p[8];
  #pragma unroll
  for (int j = 0; j < 8; ++j) p[j] = f2bf((y[j] - m) * rstd * gg[j] + bb[j]);
  o4.x = p[0] | (p[1] << 16); o4.y = p[2] | (p[3] << 16);
  o4.z = p[4] | (p[5] << 16); o4.w = p[6] | (p[7] << 16);
  *reinterpret_cast<uint4*>(lnm + hb) = o4;
}

// ---------------- gemm_pre: 64 blocks = gemm_cat(48) + W'T gemm(16), 128x128, BK=64 ----------------

__global__ __launch_bounds__(256) void gemm_pre(
    const unsigned short* __restrict__ wih_bf, const unsigned short* __restrict__ wvT,
    const unsigned short* __restrict__ wkT, const unsigned short* __restrict__ wqT,
    unsigned short* __restrict__ wcat, unsigned short* __restrict__ wpt, float scale) {
  __shared__ unsigned short sA[2][8192];
  __shared__ unsigned short sB[2][8192];
  const int blk = blockIdx.x;
  const int lane = threadIdx.x & 63, w = threadIdx.x >> 6;

  const unsigned short *A, *W;
  unsigned short* C;
  int row0, col0, ldc;
  float sc;
  if (blk < 48) {
    A = wih_bf; W = wvT; C = wcat; ldc = 1024; sc = 1.0f;
    row0 = (blk >> 2) << 7; col0 = (blk & 3) << 7;
  } else {
    A = wkT; W = wqT; C = wpt; ldc = 512; sc = scale;
    int f = blk - 48;
    row0 = (f >> 2) << 7; col0 = (f & 3) << 7;
  }
  const int K = 512;

  const int wm = (w >> 1) << 6, wn = (w & 1) << 6;
  const int lrow = lane & 15, kt = (lane >> 4) << 3;
  const int sr8 = lane >> 3, sc8 = (lane & 7) << 3;

  f32x4 acc[4][4];
  #pragma unroll
  for (int m = 0; m < 4; ++m)
    #pragma unroll
    for (int n = 0; n < 4; ++n) acc[m][n] = f32x4{0.f, 0.f, 0.f, 0.f};

  auto stage = [&](int buf, int k0) {
    #pragma unroll
    for (int i = 0; i < 4; ++i) {
      int ii = (w << 2) + i;
      int r = (ii << 3) + sr8;
      GLD16(A + (size_t)(row0 + r) * K + k0 + sc8, &sA[buf][ii * 512]);
      GLD16(W + (size_t)(col0 + r) * K + k0 + sc8, &sB[buf][ii * 512]);
    }
  };

  stage(0, 0);
  int cur = 0;
  for (int t = 0; t < 8; ++t) {
    __syncthreads();
    if (t + 1 < 8) stage(cur ^ 1, (t + 1) << 6);
    #pragma unroll
    for (int kk = 0; kk < 2; ++kk) {
      bf16x8 af[4], bfv[4];
      #pragma unroll
      for (int m = 0; m < 4; ++m)
        af[m] = *reinterpret_cast<const bf16x8*>(&sA[cur][(wm + m * 16 + lrow) * 64 + (kk << 5) + kt]);
      #pragma unroll
      for (int n = 0; n < 4; ++n)
        bfv[n] = *reinterpret_cast<const bf16x8*>(&sB[cur][(wn + n * 16 + lrow) * 64 + (kk << 5) + kt]);
      #pragma unroll
      for (int m = 0; m < 4; ++m)
        #pragma unroll
        for (int n = 0; n < 4; ++n)
          acc[m][n] = __builtin_amdgcn_mfma_f32_16x16x32_bf16(af[m], bfv[n], acc[m][n], 0, 0, 0);
    }
    cur ^= 1;
  }

  const int rb = (lane >> 4) << 2;
  #pragma unroll
  for (int m = 0; m < 4; ++m) {
    #pragma unroll
    for (int n = 0; n < 4; ++n) {
      int col = col0 + wn + n * 16 + lrow;
      #pragma unroll
      for (int r = 0; r < 4; ++r) {
        int row = row0 + wm + m * 16 + rb + r;
        C[(size_t)row * ldc + col] = f2bf(acc[m][n][r] * sc);
      }
    }
  }
}

// ---------------- q2ln: LN(slots_b) in LDS, then q2 = sn @ W' tile (BK=64) ----------------

__global__ __launch_bounds__(256) void q2ln_k(
    const float* __restrict__ slots, const float* __restrict__ g, const float* __restrict__ b,
    const unsigned short* __restrict__ wpt, unsigned short* __restrict__ q2,
    unsigned short* __restrict__ A2) {
  __shared__ unsigned short s_sn[16 * 520];
  __shared__ unsigned short sB[2][8192];
  const int b_ = blockIdx.y, ct = blockIdx.x;
  const int lane = threadIdx.x & 63, w = threadIdx.x >> 6;
  const int lrow = lane & 15, kt = (lane >> 4) << 3;
  const int sr8 = lane >> 3, sc8 = (lane & 7) << 3;

  const float4* gp = reinterpret_cast<const float4*>(g);
  const float4* bp = reinterpret_cast<const float4*>(b);
  float4 g0 = gp[lane], g1 = gp[lane + 64];
  float4 b0 = bp[lane], b1 = bp[lane + 64];
  #pragma unroll
  for (int rr = 0; rr < 4; ++rr) {
    int r = w * 4 + rr;
    const float4* rp = reinterpret_cast<const float4*>(slots + (size_t)(b_ * 16 + r) * 512);
    float4 v0 = rp[lane], v1 = rp[lane + 64];
    float s = v0.x + v0.y + v0.z + v0.w + v1.x + v1.y + v1.z + v1.w;
    float q = v0.x*v0.x + v0.y*v0.y + v0.z*v0.z + v0.w*v0.w
            + v1.x*v1.x + v1.y*v1.y + v1.z*v1.z + v1.w*v1.w;
    #pragma unroll
    for (int o = 32; o > 0; o >>= 1) { s += __shfl_xor(s, o); q += __shfl_xor(q, o); }
    float m = s * (1.0f / 512.0f);
    float rstd = rsqrtf(q * (1.0f / 512.0f) - m * m + 1e-8f);
    ushort4 o0, o1;
    o0.x = f2bf((v0.x - m) * rstd * g0.x + b0.x);
    o0.y = f2bf((v0.y - m) * rstd * g0.y + b0.y);
    o0.z = f2bf((v0.z - m) * rstd * g0.z + b0.z);
    o0.w = f2bf((v0.w - m) * rstd * g0.w + b0.w);
    o1.x = f2bf((v1.x - m) * rstd * g1.x + b1.x);
    o1.y = f2bf((v1.y - m) * rstd * g1.y + b1.y);
    o1.z = f2bf((v1.z - m) * rstd * g1.z + b1.z);
    o1.w = f2bf((v1.w - m) * rstd * g1.w + b1.w);
    *reinterpret_cast<ushort4*>(&s_sn[r * 520 + lane * 4]) = o0;
    *reinterpret_cast<ushort4*>(&s_sn[r * 520 + 256 + lane * 4]) = o1;
    if (ct == 0) {
      ushort4 c0, c1;
      c0.x = f2bf(v0.x); c0.y = f2bf(v0.y); c0.z = f2bf(v0.z); c0.w = f2bf(v0.w);
      c1.x = f2bf(v1.x); c1.y = f2bf(v1.y); c1.z = f2bf(v1.z); c1.w = f2bf(v1.w);
      unsigned short* a2r = A2 + (size_t)(b_ * 16 + r) * 1024 + 512;
      *reinterpret_cast<ushort4*>(a2r + lane * 4) = c0;
      *reinterpret_cast<ushort4*>(a2r + 256 + lane * 4) = c1;
    }
  }

  const unsigned short* Bb = wpt + (size_t)(ct << 7) * 512;
  auto stage = [&](int buf, int k0) {
    #pragma unroll
    for (int i = 0; i < 4; ++i) {
      int ii = (w << 2) + i;
      GLD16(Bb + (size_t)((ii << 3) + sr8) * 512 + k0 + sc8, &sB[buf][ii * 512]);
    }
  };

  f32x4 acc[2];
  acc[0] = f32x4{0.f, 0.f, 0.f, 0.f};
  acc[1] = f32x4{0.f, 0.f, 0.f, 0.f};

  stage(0, 0);
  int cur = 0;
  for (int t = 0; t < 8; ++t) {
    __syncthreads();
    if (t + 1 < 8) stage(cur ^ 1, (t + 1) << 6);
    #pragma unroll
    for (int kk = 0; kk < 2; ++kk) {
      bf16x8 af = *reinterpret_cast<const bf16x8*>(&s_sn[lrow * 520 + (t << 6) + (kk << 5) + kt]);
      #pragma unroll
      for (int ni = 0; ni < 2; ++ni) {
        bf16x8 bfv = *reinterpret_cast<const bf16x8*>(
            &sB[cur][((w * 2 + ni) * 16 + lrow) * 64 + (kk << 5) + kt]);
        acc[ni] = __builtin_amdgcn_mfma_f32_16x16x32_bf16(af, bfv, acc[ni], 0, 0, 0);
      }
    }
    cur ^= 1;
  }

  const int rb = (lane >> 4) << 2;
  #pragma unroll
  for (int ni = 0; ni < 2; ++ni) {
    int col = (ct << 7) + (w * 2 + ni) * 16 + lrow;
    #pragma unroll
    for (int r = 0; r < 4; ++r) {
      int s = rb + r;
      q2[(size_t)((b_ << 4) + s) * 512 + col] = f2bf(acc[ni][r]);
    }
  }
}

// ---------------- logits + per-chunk softmax stats (bf16 out, BK=64) ----------------

__global__ __launch_bounds__(256) void logits_k(
    const unsigned short* __restrict__ q2, const unsigned short* __restrict__ x,
    unsigned short* __restrict__ out, float* __restrict__ lstats) {
  __shared__ unsigned short sA[2][1024];
  __shared__ unsigned short sB[2][8192];
  __shared__ float sstat[16][4][2];
  const int b = blockIdx.y, nt = blockIdx.x;
  const int lane = threadIdx.x & 63, w = threadIdx.x >> 6;
  const int lrow = lane & 15, kt = (lane >> 4) << 3;
  const int sr8 = lane >> 3, sc8 = (lane & 7) << 3;
  const unsigned short* Ab = q2 + ((size_t)b << 13);
  const unsigned short* Bb = x + (((size_t)(b << 10) + (nt << 7)) << 9);

  f32x4 acc[2];
  acc[0] = f32x4{0.f, 0.f, 0.f, 0.f};
  acc[1] = f32x4{0.f, 0.f, 0.f, 0.f};

  auto stage = [&](int buf, int k0) {
    #pragma unroll
    for (int i = 0; i < 4; ++i) {
      int ii = (w << 2) + i;
      GLD16(Bb + (size_t)((ii << 3) + sr8) * 512 + k0 + sc8, &sB[buf][ii * 512]);
    }
    if (w == 0) {
      #pragma unroll
      for (int i = 0; i < 2; ++i)
        GLD16(Ab + (size_t)((i << 3) + sr8) * 512 + k0 + sc8, &sA[buf][i * 512]);
    }
  };

  stage(0, 0);
  int cur = 0;
  for (int t = 0; t < 8; ++t) {
    __syncthreads();
    if (t + 1 < 8) stage(cur ^ 1, (t + 1) << 6);
    #pragma unroll
    for (int kk = 0; kk < 2; ++kk) {
      bf16x8 af = *reinterpret_cast<const bf16x8*>(&sA[cur][lrow * 64 + (kk << 5) + kt]);
      #pragma unroll
      for (int ni = 0; ni < 2; ++ni) {
        bf16x8 bfv = *reinterpret_cast<const bf16x8*>(
            &sB[cur][((w * 2 + ni) * 16 + lrow) * 64 + (kk << 5) + kt]);
        acc[ni] = __builtin_amdgcn_mfma_f32_16x16x32_bf16(af, bfv, acc[ni], 0, 0, 0);
      }
    }
    cur ^= 1;
  }

  const int rb = (lane >> 4) << 2;
  unsigned short lv[2][4];
  #pragma unroll
  for (int ni = 0; ni < 2; ++ni) {
    int n = (nt << 7) + (w * 2 + ni) * 16 + lrow;
    #pragma unroll
    for (int r = 0; r < 4; ++r) {
      unsigned short u = f2bf(acc[ni][r]);
      lv[ni][r] = u;
      out[(size_t)((b << 4) + rb + r) * 1024 + n] = u;
    }
  }
  #pragma unroll
  for (int r = 0; r < 4; ++r) {
    float v0 = bf2f(lv[0][r]), v1 = bf2f(lv[1][r]);
    float m = fmaxf(v0, v1);
    #pragma unroll
    for (int o = 1; o < 16; o <<= 1) m = fmaxf(m, __shfl_xor(m, o));
    float l = __expf(v0 - m) + __expf(v1 - m);
    #pragma unroll
    for (int o = 1; o < 16; o <<= 1) l += __shfl_xor(l, o);
    if (lrow == 0) { sstat[rb + r][w][0] = m; sstat[rb + r][w][1] = l; }
  }
  __syncthreads();
  if (threadIdx.x < 16) {
    int s = threadIdx.x;
    float m = sstat[s][0][0];
    #pragma unroll
    for (int c = 1; c < 4; ++c) m = fmaxf(m, sstat[s][c][0]);
    float l = 0.f;
    #pragma unroll
    for (int c = 0; c < 4; ++c) l += sstat[s][c][1] * __expf(sstat[s][c][0] - m);
    float* lp = lstats + (((size_t)(b << 4) + s) * 8 + nt) * 2;
    lp[0] = m; lp[1] = l;
  }
}

// ---------------- pv_sm: stats-combine + colnorm (LDS attn) + ax MFMA vs xT ----------------

__global__ __launch_bounds__(256) void pv_sm_k(
    const unsigned short* __restrict__ logits, const float* __restrict__ lstats,
    const unsigned short* __restrict__ xT, unsigned short* __restrict__ A2) {
  __shared__ float s_mi[16][2];
  __shared__ unsigned short s_at[16 * 1032];
  __shared__ unsigned short sA[2][8192];
  const int b_ = blockIdx.y, et = blockIdx.x;
  const int lane = threadIdx.x & 63, w = threadIdx.x >> 6;
  const int lrow = lane & 15, kt = (lane >> 4) << 3;
  const int sr8 = lane >> 3, sc8 = (lane & 7) << 3;
  const unsigned short* lg = logits + ((size_t)b_ << 14);

  if (threadIdx.x < 16) {
    int s = threadIdx.x;
    const float* lp = lstats + (((size_t)(b_ << 4) + s) * 8) * 2;
    float m = lp[0];
    #pragma unroll
    for (int c = 1; c < 8; ++c) m = fmaxf(m, lp[c * 2]);
    float l = 0.f;
    #pragma unroll
    for (int c = 0; c < 8; ++c) l += lp[c * 2 + 1] * __expf(lp[c * 2] - m);
    s_mi[s][0] = m; s_mi[s][1] = 1.0f / l;
  }
  __syncthreads();

  #pragma unroll
  for (int j = 0; j < 4; ++j) {
    int c = threadIdx.x + (j << 8);
    float e[16];
    float cs = 0.f;
    #pragma unroll
    for (int s = 0; s < 16; ++s) {
      e[s] = __expf(bf2f(lg[(size_t)s * 1024 + c]) - s_mi[s][0]) * s_mi[s][1];
      cs += e[s];
    }
    float rv = 1.0f / (cs + 1e-8f);
    #pragma unroll
    for (int s = 0; s < 16; ++s) s_at[s * 1032 + c] = f2bf(e[s] * rv);
  }

  const unsigned short* Ab = xT + ((size_t)b_ << 19) + (size_t)(et << 7) * 1024;
  auto stage = [&](int buf, int k0) {
    #pragma unroll
    for (int i = 0; i < 4; ++i) {
      int ii = (w << 2) + i;
      GLD16(Ab + (size_t)((ii << 3) + sr8) * 1024 + k0 + sc8, &sA[buf][ii * 512]);
    }
  };

  f32x4 acc[2];
  acc[0] = f32x4{0.f, 0.f, 0.f, 0.f};
  acc[1] = f32x4{0.f, 0.f, 0.f, 0.f};

  stage(0, 0);
  int cur = 0;
  for (int t = 0; t < 16; ++t) {
    __syncthreads();
    if (t + 1 < 16) stage(cur ^ 1, (t + 1) << 6);
    #pragma unroll
    for (int kk = 0; kk < 2; ++kk) {
      bf16x8 bfv = *reinterpret_cast<const bf16x8*>(&s_at[lrow * 1032 + (t << 6) + (kk << 5) + kt]);
      #pragma unroll
      for (int mi = 0; mi < 2; ++mi) {
        bf16x8 af = *reinterpret_cast<const bf16x8*>(
            &sA[cur][((w * 2 + mi) * 16 + lrow) * 64 + (kk << 5) + kt]);
        acc[mi] = __builtin_amdgcn_mfma_f32_16x16x32_bf16(af, bfv, acc[mi], 0, 0, 0);
      }
    }
    cur ^= 1;
  }

  const int rb = (lane >> 4) << 2;
  const int s = lrow;
  #pragma unroll
  for (int mi = 0; mi < 2; ++mi) {
    int e0 = (et << 7) + (w * 2 + mi) * 16 + rb;
    ushort4 o;
    o.x = f2bf(acc[mi][0]); o.y = f2bf(acc[mi][1]);
    o.z = f2bf(acc[mi][2]); o.w = f2bf(acc[mi][3]);
    *reinterpret_cast<ushort4*>(&A2[(size_t)((b_ << 4) + s) * 1024 + e0]) = o;
  }
}

// ---------------- MFMA GEMM 64x64 (slot-sized GEMMs, BK=64) ----------------
// GATES=1: N=2048 gates GEMM; cols [1024,1536) use K=[0,512), [1536,2048) K=[512,1024)

template<int BIAS, int RELU, int ADDSRC, int OUTBF16, int GATES>
__global__ __launch_bounds__(256) void gemm_sm(
    const unsigned short* __restrict__ A, const unsigned short* __restrict__ W,
    const float* __restrict__ bias, const float* __restrict__ addsrc,
    void* __restrict__ Cout, int M, int N, int K) {
  __shared__ unsigned short sA[2][4096];
  __shared__ unsigned short sB[2][4096];
  const int tid = threadIdx.x;
  const int lane = tid & 63, w = tid >> 6;

  int nwg = gridDim.x * gridDim.y;
  int flat = blockIdx.y * gridDim.x + blockIdx.x;
  if ((nwg & 7) == 0) { int c = nwg >> 3; flat = (flat & 7) * c + (flat >> 3); }
  const int row0 = (flat / gridDim.x) << 6;
  const int col0 = (flat % gridDim.x) << 6;

  int kb = 0, ke = K;
  if (GATES) {
    if (col0 >= 1536)      { kb = 512; ke = 1024; }
    else if (col0 >= 1024) { kb = 0;   ke = 512;  }
  }

  const int lrow = lane & 15, kt = (lane >> 4) << 3;
  const int sr8 = lane >> 3, sc8 = (lane & 7) << 3;

  f32x4 acc[4];
  #pragma unroll
  for (int m = 0; m < 4; ++m) acc[m] = f32x4{0.f, 0.f, 0.f, 0.f};

  auto stage = [&](int buf, int k0) {
    #pragma unroll
    for (int i = 0; i < 2; ++i) {
      int ii = (w << 1) + i;
      int r = (ii << 3) + sr8;
      GLD16(A + (size_t)(row0 + r) * K + k0 + sc8, &sA[buf][ii * 512]);
      GLD16(W + (size_t)(col0 + r) * K + k0 + sc8, &sB[buf][ii * 512]);
    }
  };

  stage(0, kb);
  const int nt = (ke - kb) >> 6;
  int cur = 0;
  for (int t = 0; t < nt; ++t) {
    __syncthreads();
    if (t + 1 < nt) stage(cur ^ 1, kb + ((t + 1) << 6));
    #pragma unroll
    for (int kk = 0; kk < 2; ++kk) {
      bf16x8 bfv = *reinterpret_cast<const bf16x8*>(
          &sB[cur][((w << 4) + lrow) * 64 + (kk << 5) + kt]);
      #pragma unroll
      for (int m = 0; m < 4; ++m) {
        bf16x8 af = *reinterpret_cast<const bf16x8*>(
            &sA[cur][(m * 16 + lrow) * 64 + (kk << 5) + kt]);
        acc[m] = __builtin_amdgcn_mfma_f32_16x16x32_bf16(af, bfv, acc[m], 0, 0, 0);
      }
    }
    cur ^= 1;
  }

  const int rb = (lane >> 4) << 2;
  const int col = col0 + (w << 4) + lrow;
  float bv = BIAS ? bias[col] : 0.0f;
  #pragma unroll
  for (int m = 0; m < 4; ++m) {
    #pragma unroll
    for (int r = 0; r < 4; ++r) {
      int row = row0 + m * 16 + rb + r;
      float v = acc[m][r] + bv;
      if (ADDSRC) v += addsrc[(size_t)row * N + col];
      if (RELU) v = fmaxf(v, 0.0f);
      if (OUTBF16) ((unsigned short*)Cout)[(size_t)row * N + col] = f2bf(v);
      else ((float*)Cout)[(size_t)row * N + col] = v;
    }
  }
}

// ---------------- host launch ----------------

extern "C" void kernel_launch(void* const* d_in, const int* in_sizes, int n_in,
                              void* d_out, int out_size, void* d_ws, size_t ws_size,
                              hipStream_t stream) {
  const float* inputs  = (const float*)d_in[0];
  const float* noise   = (const float*)d_in[1];
  const float* slot_mu = (const float*)d_in[2];
  const float* slot_ls = (const float*)d_in[3];
  const float* ln_in_g = (const float*)d_in[4];
  const float* ln_in_b = (const float*)d_in[5];
  const float* ln_s_g  = (const float*)d_in[6];
  const float* ln_s_b  = (const float*)d_in[7];
  const float* ln_m_g  = (const float*)d_in[8];
  const float* ln_m_b  = (const float*)d_in[9];
  const float* Wq   = (const float*)d_in[10];
  const float* Wk   = (const float*)d_in[11];
  const float* Wv   = (const float*)d_in[12];
  const float* w_ih = (const float*)d_in[13];
  const float* w_hh = (const float*)d_in[14];
  const float* b_ih = (const float*)d_in[15];
  const float* b_hh = (const float*)d_in[16];
  const float* w1   = (const float*)d_in[17];
  const float* b1   = (const float*)d_in[18];
  const float* w2   = (const float*)d_in[19];
  const float* b2   = (const float*)d_in[20];

  const int BN = 65536, BS = 1024;

  uintptr_t base = (uintptr_t)d_ws;
  auto alloc = [&](size_t bytes) {
    void* p = (void*)base;
    base += (bytes + 255) & ~(size_t)255;
    return p;
  };
  unsigned short* x_bf    = (unsigned short*)alloc((size_t)BN * 512 * 2);
  unsigned short* xT      = (unsigned short*)alloc((size_t)64 * 512 * 1024 * 2);
  unsigned short* wqT     = (unsigned short*)alloc(512 * 512 * 2);
  unsigned short* wkT     = (unsigned short*)alloc(512 * 512 * 2);
  unsigned short* wvT     = (unsigned short*)alloc(512 * 512 * 2);
  unsigned short* wpt     = (unsigned short*)alloc(512 * 512 * 2);
  unsigned short* wih_bf  = (unsigned short*)alloc((size_t)1536 * 512 * 2);
  unsigned short* wcat_bf = (unsigned short*)alloc((size_t)2048 * 1024 * 2);
  float*          bcat    = (float*)alloc(2048 * 4);
  unsigned short* w1_bf   = (unsigned short*)alloc(512 * 512 * 2);
  unsigned short* w2_bf   = (unsigned short*)alloc(512 * 512 * 2);
  float*          slots   = (float*)alloc((size_t)BS * 512 * 4);
  unsigned short* A2      = (unsigned short*)alloc((size_t)BS * 1024 * 2);
  unsigned short* q2_bf   = (unsigned short*)alloc((size_t)BS * 512 * 2);
  unsigned short* logits  = (unsigned short*)alloc((size_t)64 * 16 * 1024 * 2);
  float*          lstats  = (float*)alloc((size_t)64 * 16 * 8 * 2 * 4);
  float*          gates   = (float*)alloc((size_t)BS * 2048 * 4);
  float*          sgru    = (float*)alloc((size_t)BS * 512 * 4);
  unsigned short* lnm_bf  = (unsigned short*)alloc((size_t)BS * 512 * 2);
  unsigned short* h_bf    = (unsigned short*)alloc((size_t)BS * 512 * 2);
  (void)ws_size; (void)n_in; (void)in_sizes; (void)out_size;

  const float scale = 0.044194173824159216f;  // 512^-0.5

  // prologue (3 dispatches)
  wprep_k<<<13064, 256, 0, stream>>>(w1, w2, w_ih, w_hh, b_ih, b_hh,
                                     slot_mu, slot_ls, noise, Wq, Wk, Wv,
                                     w1_bf, w2_bf, wih_bf, wcat_bf, bcat, slots,
                                     wqT, wkT, wvT);
  gemm_pre<<<64, 256, 0, stream>>>(wih_bf, wvT, wkT, wqT, wcat_bf, wpt, scale);
  ln_xt_k<<<2048, 256, 0, stream>>>(inputs, ln_in_g, ln_in_b, x_bf, xT);

  for (int it = 0; it < 3; ++it) {
    q2ln_k<<<dim3(4, 64), 256, 0, stream>>>(slots, ln_s_g, ln_s_b, wpt, q2_bf, A2);
    logits_k<<<dim3(8, 64), 256, 0, stream>>>(q2_bf, x_bf, logits, lstats);
    pv_sm_k<<<dim3(4, 64), 256, 0, stream>>>(logits, lstats, xT, A2);
    gemm_sm<1,0,0,0,1><<<dim3(32, 16), 256, 0, stream>>>(
        A2, wcat_bf, bcat, nullptr, gates, BS, 2048, 1024);
    gru_ln_k<<<256, 256, 0, stream>>>(gates, slots, ln_m_g, ln_m_b, sgru, lnm_bf);
    gemm_sm<1,1,0,1,0><<<dim3(8, 16), 256, 0, stream>>>(
        lnm_bf, w1_bf, b1, nullptr, h_bf, BS, 512, 512);
    float* slots_out = (it == 2) ? (float*)d_out : slots;
    gemm_sm<1,0,1,0,0><<<dim3(8, 16), 256, 0, stream>>>(
        h_bf, w2_bf, b2, sgru, slots_out, BS, 512, 512);
  }
}

// Round 16
// 307.645 us; speedup vs baseline: 1.0179x; 1.0044x over previous
//
#include <hip/hip_runtime.h>
#include <hip/hip_bf16.h>
#include <cstdint>
#include <cstddef>

// Shapes fixed: B=64, N=1024, D=512, S=16, 3 iterations.
// Algebra: logits = sn·W'·x^T, W' = scale·Wq^T·Wk   (k never materialized)
//          ax = attn·x;  upd@Wih^T = ax@(Wih·Wv)^T  (v never materialized)
// R16: ln_xt with 64-row blocks / 512 threads -> xT written in 128B bursts
//      (R15's 32-row version wrote 64B slices; conflicts were ruled out).

typedef __bf16 bf16x8 __attribute__((ext_vector_type(8)));
typedef float f32x4 __attribute__((ext_vector_type(4)));

__device__ __forceinline__ float bf2f(unsigned int u) {
  union { unsigned int i; float f; } v; v.i = u << 16; return v.f;
}
__device__ __forceinline__ unsigned short f2bf(float x) {
  __hip_bfloat16 h = __float2bfloat16(x);
  unsigned short u;
  __builtin_memcpy(&u, &h, 2);
  return u;
}

#define GLD16(gp, lp)                                                       \
  __builtin_amdgcn_global_load_lds(                                         \
      (const __attribute__((address_space(1))) void*)(gp),                  \
      (__attribute__((address_space(3))) void*)(lp), 16, 0, 0)

// ---------------- merged prep (segmented grid, 13064 blocks) ----------------

__global__ void wprep_k(const float* __restrict__ w1, const float* __restrict__ w2,
                        const float* __restrict__ wih, const float* __restrict__ whh,
                        const float* __restrict__ bih, const float* __restrict__ bhh,
                        const float* __restrict__ mu, const float* __restrict__ ls,
                        const float* __restrict__ noise,
                        const float* __restrict__ Wq, const float* __restrict__ Wk,
                        const float* __restrict__ Wv,
                        unsigned short* __restrict__ w1_bf, unsigned short* __restrict__ w2_bf,
                        unsigned short* __restrict__ wih_bf, unsigned short* __restrict__ wcat,
                        float* __restrict__ bcat, float* __restrict__ slots,
                        unsigned short* __restrict__ wqT, unsigned short* __restrict__ wkT,
                        unsigned short* __restrict__ wvT) {
  __shared__ float tt[32][33];
  int blk = blockIdx.x, t = threadIdx.x;
  if (blk < 1024) {
    int i = blk * 256 + t; w1_bf[i] = f2bf(w1[i]);
  } else if (blk < 2048) {
    int i = (blk - 1024) * 256 + t; w2_bf[i] = f2bf(w2[i]);
  } else if (blk < 5120) {
    int i = (blk - 2048) * 256 + t; wih_bf[i] = f2bf(wih[i]);
  } else if (blk < 7168) {
    int i = (blk - 5120) * 256 + t;
    int j = i >> 9, d = i & 511;
    wcat[(size_t)j * 1024 + 512 + d] = f2bf(whh[(size_t)j * 512 + d]);
  } else if (blk < 8192) {
    int i = (blk - 7168) * 256 + t;
    int j = i >> 9, d = i & 511;
    wcat[(size_t)(1536 + j) * 1024 + 512 + d] = f2bf(whh[(size_t)(1024 + j) * 512 + d]);
  } else if (blk < 10240) {
    int i = (blk - 8192) * 256 + t;
    if (i < 262144) {
      int j = i >> 9, d = i & 511;
      wcat[(size_t)(1536 + j) * 1024 + d] = 0;
    } else {
      int k = i - 262144;
      int j = k >> 9, d = k & 511;
      wcat[(size_t)(1024 + j) * 1024 + 512 + d] = 0;
    }
  } else if (blk < 10248) {
    int j = (blk - 10240) * 256 + t;
    float v;
    if (j < 1024)      v = bih[j] + bhh[j];
    else if (j < 1536) v = bih[j];
    else               v = bhh[j - 512];
    bcat[j] = v;
  } else if (blk < 12296) {
    int i = (blk - 10248) * 256 + t;
    int d = i & 511;
    slots[i] = mu[d] + expf(ls[d]) * noise[i];
  } else {
    int blk2 = blk - 12296;              // 768 transpose blocks
    int mat = blk2 >> 8, tile = blk2 & 255;
    const float* in = mat == 0 ? Wq : (mat == 1 ? Wk : Wv);
    unsigned short* out = mat == 0 ? wqT : (mat == 1 ? wkT : wvT);
    int c0 = (tile & 15) << 5, r0 = (tile >> 4) << 5;
    int tx = t & 31, ty = t >> 5;
    #pragma unroll
    for (int i = 0; i < 4; ++i)
      tt[ty + 8 * i][tx] = in[(size_t)(r0 + ty + 8 * i) * 512 + c0 + tx];
    __syncthreads();
    #pragma unroll
    for (int i = 0; i < 4; ++i)
      out[(size_t)(c0 + ty + 8 * i) * 512 + r0 + tx] = f2bf(tt[tx][ty + 8 * i]);
  }
}

// ---------------- ln_xt: LN(inputs) -> x_bf AND xT; 64 rows/block, 512 thr ----------------
// grid 1024 blocks (64 rows each, never straddling a batch), LDS 66.5KB.
// LDS col swizzle: c ^ (((r>>3)&7)<<3). xT written in 128B bursts.

__global__ __launch_bounds__(512) void ln_xt_k(
    const float* __restrict__ in, const float* __restrict__ g, const float* __restrict__ b,
    unsigned short* __restrict__ x_bf, unsigned short* __restrict__ xT) {
  __shared__ unsigned short tbuf[64 * 520];
  const int row0 = blockIdx.x << 6;
  const int bb_ = row0 >> 10;
  const int n0 = row0 & 1023;
  const int w = threadIdx.x >> 6, lane = threadIdx.x & 63;

  const float4* gp = reinterpret_cast<const float4*>(g);
  const float4* bp = reinterpret_cast<const float4*>(b);
  float4 g0 = gp[lane], g1 = gp[lane + 64];
  float4 b0 = bp[lane], b1 = bp[lane + 64];

  #pragma unroll
  for (int i = 0; i < 8; ++i) {
    int r = (w << 3) + i;
    int row = row0 + r;
    const float4* rp = reinterpret_cast<const float4*>(in + (size_t)row * 512);
    float4 v0 = rp[lane], v1 = rp[lane + 64];
    float s = v0.x + v0.y + v0.z + v0.w + v1.x + v1.y + v1.z + v1.w;
    float q = v0.x*v0.x + v0.y*v0.y + v0.z*v0.z + v0.w*v0.w
            + v1.x*v1.x + v1.y*v1.y + v1.z*v1.z + v1.w*v1.w;
    #pragma unroll
    for (int o = 32; o > 0; o >>= 1) { s += __shfl_xor(s, o); q += __shfl_xor(q, o); }
    float m = s * (1.0f / 512.0f);
    float rstd = rsqrtf(q * (1.0f / 512.0f) - m * m + 1e-8f);
    ushort4 o0, o1;
    o0.x = f2bf((v0.x - m) * rstd * g0.x + b0.x);
    o0.y = f2bf((v0.y - m) * rstd * g0.y + b0.y);
    o0.z = f2bf((v0.z - m) * rstd * g0.z + b0.z);
    o0.w = f2bf((v0.w - m) * rstd * g0.w + b0.w);
    o1.x = f2bf((v1.x - m) * rstd * g1.x + b1.x);
    o1.y = f2bf((v1.y - m) * rstd * g1.y + b1.y);
    o1.z = f2bf((v1.z - m) * rstd * g1.z + b1.z);
    o1.w = f2bf((v1.w - m) * rstd * g1.w + b1.w);
    ushort4* op = reinterpret_cast<ushort4*>(x_bf + (size_t)row * 512);
    op[lane] = o0; op[lane + 64] = o1;
    const int key = ((r >> 3) & 7) << 3;
    *reinterpret_cast<ushort4*>(&tbuf[r * 520 + ((lane * 4) ^ key)]) = o0;
    *reinterpret_cast<ushort4*>(&tbuf[r * 520 + ((256 + lane * 4) ^ key)]) = o1;
  }
  __syncthreads();

  // transpose: thread (e_lo = tid>>3, n8 = (tid&7)*8); 8 e-passes.
  // 8 adjacent lanes cover 64 consecutive n -> 128B burst per e-row.
  const int e_lo = threadIdx.x >> 3;          // 0..63
  const int n8 = (threadIdx.x & 7) << 3;      // 0..56
  const int key = ((n8 >> 3) & 7) << 3;       // constant over rows n8..n8+7
  #pragma unroll
  for (int et = 0; et < 8; ++et) {
    int e = (et << 6) + e_lo;
    int es = e ^ key;
    ushort4 a, c;
    #pragma unroll
    for (int j = 0; j < 4; ++j) ((unsigned short*)&a)[j] = tbuf[(n8 + j) * 520 + es];
    #pragma unroll
    for (int j = 0; j < 4; ++j) ((unsigned short*)&c)[j] = tbuf[(n8 + 4 + j) * 520 + es];
    unsigned short* o = xT + ((size_t)(bb_ << 9) + e) * 1024 + n0 + n8;
    *reinterpret_cast<ushort4*>(o) = a;
    *reinterpret_cast<ushort4*>(o + 4) = c;
  }
}

// GRU (fused-gates layout) + LN
__global__ __launch_bounds__(256) void gru_ln_k(
    const float* __restrict__ gates, const float* __restrict__ hp,
    const float* __restrict__ g, const float* __restrict__ b,
    float* __restrict__ sgru, unsigned short* __restrict__ lnm) {
  int w = threadIdx.x >> 6, lane = threadIdx.x & 63;
  int row = (blockIdx.x << 2) + w;
  size_t gb = (size_t)row * 2048 + (lane << 3);
  size_t hb = (size_t)row * 512 + (lane << 3);
  float rs[8], zs[8], in_[8], hn[8], hv[8], y[8];
  #pragma unroll
  for (int c = 0; c < 2; ++c) {
    *reinterpret_cast<float4*>(rs + 4*c)  = *reinterpret_cast<const float4*>(gates + gb + 4*c);
    *reinterpret_cast<float4*>(zs + 4*c)  = *reinterpret_cast<const float4*>(gates + gb + 512 + 4*c);
    *reinterpret_cast<float4*>(in_ + 4*c) = *reinterpret_cast<const float4*>(gates + gb + 1024 + 4*c);
    *reinterpret_cast<float4*>(hn + 4*c)  = *reinterpret_cast<const float4*>(gates + gb + 1536 + 4*c);
    *reinterpret_cast<float4*>(hv + 4*c)  = *reinterpret_cast<const float4*>(hp + hb + 4*c);
  }
  float s = 0.f, q = 0.f;
  #pragma unroll
  for (int j = 0; j < 8; ++j) {
    float r = 1.0f / (1.0f + expf(-rs[j]));
    float z = 1.0f / (1.0f + expf(-zs[j]));
    float n = tanhf(in_[j] + r * hn[j]);
    float h = (1.0f - z) * n + z * hv[j];
    y[j] = h; s += h; q += h * h;
  }
  #pragma unroll
  for (int o = 32; o > 0; o >>= 1) { s += __shfl_xor(s, o); q += __shfl_xor(q, o); }
  float m = s * (1.0f / 512.0f);
  float rstd = rsqrtf(q * (1.0f / 512.0f) - m * m + 1e-8f);
  const float* gg = g + (lane << 3);
  const float* bb = b + (lane << 3);
  #pragma unroll
  for (int c = 0; c < 2; ++c)
    *reinterpret_cast<float4*>(sgru + hb + 4*c) = *reinterpret_cast<const float4*>(y + 4*c);
  uint4 o4;
  unsigned int p[8];
  #pragma unroll
  for (int j = 0; j < 8; ++j) p[j] = f2bf((y[j] - m) * rstd * gg[j] + bb[j]);
  o4.x = p[0] | (p[1] << 16); o4.y = p[2] | (p[3] << 16);
  o4.z = p[4] | (p[5] << 16); o4.w = p[6] | (p[7] << 16);
  *reinterpret_cast<uint4*>(lnm + hb) = o4;
}

// ---------------- gemm_pre: 64 blocks = gemm_cat(48) + W'T gemm(16), 128x128, BK=64 ----------------

__global__ __launch_bounds__(256) void gemm_pre(
    const unsigned short* __restrict__ wih_bf, const unsigned short* __restrict__ wvT,
    const unsigned short* __restrict__ wkT, const unsigned short* __restrict__ wqT,
    unsigned short* __restrict__ wcat, unsigned short* __restrict__ wpt, float scale) {
  __shared__ unsigned short sA[2][8192];
  __shared__ unsigned short sB[2][8192];
  const int blk = blockIdx.x;
  const int lane = threadIdx.x & 63, w = threadIdx.x >> 6;

  const unsigned short *A, *W;
  unsigned short* C;
  int row0, col0, ldc;
  float sc;
  if (blk < 48) {
    A = wih_bf; W = wvT; C = wcat; ldc = 1024; sc = 1.0f;
    row0 = (blk >> 2) << 7; col0 = (blk & 3) << 7;
  } else {
    A = wkT; W = wqT; C = wpt; ldc = 512; sc = scale;
    int f = blk - 48;
    row0 = (f >> 2) << 7; col0 = (f & 3) << 7;
  }
  const int K = 512;

  const int wm = (w >> 1) << 6, wn = (w & 1) << 6;
  const int lrow = lane & 15, kt = (lane >> 4) << 3;
  const int sr8 = lane >> 3, sc8 = (lane & 7) << 3;

  f32x4 acc[4][4];
  #pragma unroll
  for (int m = 0; m < 4; ++m)
    #pragma unroll
    for (int n = 0; n < 4; ++n) acc[m][n] = f32x4{0.f, 0.f, 0.f, 0.f};

  auto stage = [&](int buf, int k0) {
    #pragma unroll
    for (int i = 0; i < 4; ++i) {
      int ii = (w << 2) + i;
      int r = (ii << 3) + sr8;
      GLD16(A + (size_t)(row0 + r) * K + k0 + sc8, &sA[buf][ii * 512]);
      GLD16(W + (size_t)(col0 + r) * K + k0 + sc8, &sB[buf][ii * 512]);
    }
  };

  stage(0, 0);
  int cur = 0;
  for (int t = 0; t < 8; ++t) {
    __syncthreads();
    if (t + 1 < 8) stage(cur ^ 1, (t + 1) << 6);
    #pragma unroll
    for (int kk = 0; kk < 2; ++kk) {
      bf16x8 af[4], bfv[4];
      #pragma unroll
      for (int m = 0; m < 4; ++m)
        af[m] = *reinterpret_cast<const bf16x8*>(&sA[cur][(wm + m * 16 + lrow) * 64 + (kk << 5) + kt]);
      #pragma unroll
      for (int n = 0; n < 4; ++n)
        bfv[n] = *reinterpret_cast<const bf16x8*>(&sB[cur][(wn + n * 16 + lrow) * 64 + (kk << 5) + kt]);
      #pragma unroll
      for (int m = 0; m < 4; ++m)
        #pragma unroll
        for (int n = 0; n < 4; ++n)
          acc[m][n] = __builtin_amdgcn_mfma_f32_16x16x32_bf16(af[m], bfv[n], acc[m][n], 0, 0, 0);
    }
    cur ^= 1;
  }

  const int rb = (lane >> 4) << 2;
  #pragma unroll
  for (int m = 0; m < 4; ++m) {
    #pragma unroll
    for (int n = 0; n < 4; ++n) {
      int col = col0 + wn + n * 16 + lrow;
      #pragma unroll
      for (int r = 0; r < 4; ++r) {
        int row = row0 + wm + m * 16 + rb + r;
        C[(size_t)row * ldc + col] = f2bf(acc[m][n][r] * sc);
      }
    }
  }
}

// ---------------- q2ln: LN(slots_b) in LDS, then q2 = sn @ W' tile (BK=64) ----------------

__global__ __launch_bounds__(256) void q2ln_k(
    const float* __restrict__ slots, const float* __restrict__ g, const float* __restrict__ b,
    const unsigned short* __restrict__ wpt, unsigned short* __restrict__ q2,
    unsigned short* __restrict__ A2) {
  __shared__ unsigned short s_sn[16 * 520];
  __shared__ unsigned short sB[2][8192];
  const int b_ = blockIdx.y, ct = blockIdx.x;
  const int lane = threadIdx.x & 63, w = threadIdx.x >> 6;
  const int lrow = lane & 15, kt = (lane >> 4) << 3;
  const int sr8 = lane >> 3, sc8 = (lane & 7) << 3;

  const float4* gp = reinterpret_cast<const float4*>(g);
  const float4* bp = reinterpret_cast<const float4*>(b);
  float4 g0 = gp[lane], g1 = gp[lane + 64];
  float4 b0 = bp[lane], b1 = bp[lane + 64];
  #pragma unroll
  for (int rr = 0; rr < 4; ++rr) {
    int r = w * 4 + rr;
    const float4* rp = reinterpret_cast<const float4*>(slots + (size_t)(b_ * 16 + r) * 512);
    float4 v0 = rp[lane], v1 = rp[lane + 64];
    float s = v0.x + v0.y + v0.z + v0.w + v1.x + v1.y + v1.z + v1.w;
    float q = v0.x*v0.x + v0.y*v0.y + v0.z*v0.z + v0.w*v0.w
            + v1.x*v1.x + v1.y*v1.y + v1.z*v1.z + v1.w*v1.w;
    #pragma unroll
    for (int o = 32; o > 0; o >>= 1) { s += __shfl_xor(s, o); q += __shfl_xor(q, o); }
    float m = s * (1.0f / 512.0f);
    float rstd = rsqrtf(q * (1.0f / 512.0f) - m * m + 1e-8f);
    ushort4 o0, o1;
    o0.x = f2bf((v0.x - m) * rstd * g0.x + b0.x);
    o0.y = f2bf((v0.y - m) * rstd * g0.y + b0.y);
    o0.z = f2bf((v0.z - m) * rstd * g0.z + b0.z);
    o0.w = f2bf((v0.w - m) * rstd * g0.w + b0.w);
    o1.x = f2bf((v1.x - m) * rstd * g1.x + b1.x);
    o1.y = f2bf((v1.y - m) * rstd * g1.y + b1.y);
    o1.z = f2bf((v1.z - m) * rstd * g1.z + b1.z);
    o1.w = f2bf((v1.w - m) * rstd * g1.w + b1.w);
    *reinterpret_cast<ushort4*>(&s_sn[r * 520 + lane * 4]) = o0;
    *reinterpret_cast<ushort4*>(&s_sn[r * 520 + 256 + lane * 4]) = o1;
    if (ct == 0) {
      ushort4 c0, c1;
      c0.x = f2bf(v0.x); c0.y = f2bf(v0.y); c0.z = f2bf(v0.z); c0.w = f2bf(v0.w);
      c1.x = f2bf(v1.x); c1.y = f2bf(v1.y); c1.z = f2bf(v1.z); c1.w = f2bf(v1.w);
      unsigned short* a2r = A2 + (size_t)(b_ * 16 + r) * 1024 + 512;
      *reinterpret_cast<ushort4*>(a2r + lane * 4) = c0;
      *reinterpret_cast<ushort4*>(a2r + 256 + lane * 4) = c1;
    }
  }

  const unsigned short* Bb = wpt + (size_t)(ct << 7) * 512;
  auto stage = [&](int buf, int k0) {
    #pragma unroll
    for (int i = 0; i < 4; ++i) {
      int ii = (w << 2) + i;
      GLD16(Bb + (size_t)((ii << 3) + sr8) * 512 + k0 + sc8, &sB[buf][ii * 512]);
    }
  };

  f32x4 acc[2];
  acc[0] = f32x4{0.f, 0.f, 0.f, 0.f};
  acc[1] = f32x4{0.f, 0.f, 0.f, 0.f};

  stage(0, 0);
  int cur = 0;
  for (int t = 0; t < 8; ++t) {
    __syncthreads();
    if (t + 1 < 8) stage(cur ^ 1, (t + 1) << 6);
    #pragma unroll
    for (int kk = 0; kk < 2; ++kk) {
      bf16x8 af = *reinterpret_cast<const bf16x8*>(&s_sn[lrow * 520 + (t << 6) + (kk << 5) + kt]);
      #pragma unroll
      for (int ni = 0; ni < 2; ++ni) {
        bf16x8 bfv = *reinterpret_cast<const bf16x8*>(
            &sB[cur][((w * 2 + ni) * 16 + lrow) * 64 + (kk << 5) + kt]);
        acc[ni] = __builtin_amdgcn_mfma_f32_16x16x32_bf16(af, bfv, acc[ni], 0, 0, 0);
      }
    }
    cur ^= 1;
  }

  const int rb = (lane >> 4) << 2;
  #pragma unroll
  for (int ni = 0; ni < 2; ++ni) {
    int col = (ct << 7) + (w * 2 + ni) * 16 + lrow;
    #pragma unroll
    for (int r = 0; r < 4; ++r) {
      int s = rb + r;
      q2[(size_t)((b_ << 4) + s) * 512 + col] = f2bf(acc[ni][r]);
    }
  }
}

// ---------------- logits + per-chunk softmax stats (bf16 out, BK=64) ----------------

__global__ __launch_bounds__(256) void logits_k(
    const unsigned short* __restrict__ q2, const unsigned short* __restrict__ x,
    unsigned short* __restrict__ out, float* __restrict__ lstats) {
  __shared__ unsigned short sA[2][1024];
  __shared__ unsigned short sB[2][8192];
  __shared__ float sstat[16][4][2];
  const int b = blockIdx.y, nt = blockIdx.x;
  const int lane = threadIdx.x & 63, w = threadIdx.x >> 6;
  const int lrow = lane & 15, kt = (lane >> 4) << 3;
  const int sr8 = lane >> 3, sc8 = (lane & 7) << 3;
  const unsigned short* Ab = q2 + ((size_t)b << 13);
  const unsigned short* Bb = x + (((size_t)(b << 10) + (nt << 7)) << 9);

  f32x4 acc[2];
  acc[0] = f32x4{0.f, 0.f, 0.f, 0.f};
  acc[1] = f32x4{0.f, 0.f, 0.f, 0.f};

  auto stage = [&](int buf, int k0) {
    #pragma unroll
    for (int i = 0; i < 4; ++i) {
      int ii = (w << 2) + i;
      GLD16(Bb + (size_t)((ii << 3) + sr8) * 512 + k0 + sc8, &sB[buf][ii * 512]);
    }
    if (w == 0) {
      #pragma unroll
      for (int i = 0; i < 2; ++i)
        GLD16(Ab + (size_t)((i << 3) + sr8) * 512 + k0 + sc8, &sA[buf][i * 512]);
    }
  };

  stage(0, 0);
  int cur = 0;
  for (int t = 0; t < 8; ++t) {
    __syncthreads();
    if (t + 1 < 8) stage(cur ^ 1, (t + 1) << 6);
    #pragma unroll
    for (int kk = 0; kk < 2; ++kk) {
      bf16x8 af = *reinterpret_cast<const bf16x8*>(&sA[cur][lrow * 64 + (kk << 5) + kt]);
      #pragma unroll
      for (int ni = 0; ni < 2; ++ni) {
        bf16x8 bfv = *reinterpret_cast<const bf16x8*>(
            &sB[cur][((w * 2 + ni) * 16 + lrow) * 64 + (kk << 5) + kt]);
        acc[ni] = __builtin_amdgcn_mfma_f32_16x16x32_bf16(af, bfv, acc[ni], 0, 0, 0);
      }
    }
    cur ^= 1;
  }

  const int rb = (lane >> 4) << 2;
  unsigned short lv[2][4];
  #pragma unroll
  for (int ni = 0; ni < 2; ++ni) {
    int n = (nt << 7) + (w * 2 + ni) * 16 + lrow;
    #pragma unroll
    for (int r = 0; r < 4; ++r) {
      unsigned short u = f2bf(acc[ni][r]);
      lv[ni][r] = u;
      out[(size_t)((b << 4) + rb + r) * 1024 + n] = u;
    }
  }
  #pragma unroll
  for (int r = 0; r < 4; ++r) {
    float v0 = bf2f(lv[0][r]), v1 = bf2f(lv[1][r]);
    float m = fmaxf(v0, v1);
    #pragma unroll
    for (int o = 1; o < 16; o <<= 1) m = fmaxf(m, __shfl_xor(m, o));
    float l = __expf(v0 - m) + __expf(v1 - m);
    #pragma unroll
    for (int o = 1; o < 16; o <<= 1) l += __shfl_xor(l, o);
    if (lrow == 0) { sstat[rb + r][w][0] = m; sstat[rb + r][w][1] = l; }
  }
  __syncthreads();
  if (threadIdx.x < 16) {
    int s = threadIdx.x;
    float m = sstat[s][0][0];
    #pragma unroll
    for (int c = 1; c < 4; ++c) m = fmaxf(m, sstat[s][c][0]);
    float l = 0.f;
    #pragma unroll
    for (int c = 0; c < 4; ++c) l += sstat[s][c][1] * __expf(sstat[s][c][0] - m);
    float* lp = lstats + (((size_t)(b << 4) + s) * 8 + nt) * 2;
    lp[0] = m; lp[1] = l;
  }
}

// ---------------- pv_sm: stats-combine + colnorm (LDS attn) + ax MFMA vs xT ----------------

__global__ __launch_bounds__(256) void pv_sm_k(
    const unsigned short* __restrict__ logits, const float* __restrict__ lstats,
    const unsigned short* __restrict__ xT, unsigned short* __restrict__ A2) {
  __shared__ float s_mi[16][2];
  __shared__ unsigned short s_at[16 * 1032];
  __shared__ unsigned short sA[2][8192];
  const int b_ = blockIdx.y, et = blockIdx.x;
  const int lane = threadIdx.x & 63, w = threadIdx.x >> 6;
  const int lrow = lane & 15, kt = (lane >> 4) << 3;
  const int sr8 = lane >> 3, sc8 = (lane & 7) << 3;
  const unsigned short* lg = logits + ((size_t)b_ << 14);

  if (threadIdx.x < 16) {
    int s = threadIdx.x;
    const float* lp = lstats + (((size_t)(b_ << 4) + s) * 8) * 2;
    float m = lp[0];
    #pragma unroll
    for (int c = 1; c < 8; ++c) m = fmaxf(m, lp[c * 2]);
    float l = 0.f;
    #pragma unroll
    for (int c = 0; c < 8; ++c) l += lp[c * 2 + 1] * __expf(lp[c * 2] - m);
    s_mi[s][0] = m; s_mi[s][1] = 1.0f / l;
  }
  __syncthreads();

  #pragma unroll
  for (int j = 0; j < 4; ++j) {
    int c = threadIdx.x + (j << 8);
    float e[16];
    float cs = 0.f;
    #pragma unroll
    for (int s = 0; s < 16; ++s) {
      e[s] = __expf(bf2f(lg[(size_t)s * 1024 + c]) - s_mi[s][0]) * s_mi[s][1];
      cs += e[s];
    }
    float rv = 1.0f / (cs + 1e-8f);
    #pragma unroll
    for (int s = 0; s < 16; ++s) s_at[s * 1032 + c] = f2bf(e[s] * rv);
  }

  const unsigned short* Ab = xT + ((size_t)b_ << 19) + (size_t)(et << 7) * 1024;
  auto stage = [&](int buf, int k0) {
    #pragma unroll
    for (int i = 0; i < 4; ++i) {
      int ii = (w << 2) + i;
      GLD16(Ab + (size_t)((ii << 3) + sr8) * 1024 + k0 + sc8, &sA[buf][ii * 512]);
    }
  };

  f32x4 acc[2];
  acc[0] = f32x4{0.f, 0.f, 0.f, 0.f};
  acc[1] = f32x4{0.f, 0.f, 0.f, 0.f};

  stage(0, 0);
  int cur = 0;
  for (int t = 0; t < 16; ++t) {
    __syncthreads();
    if (t + 1 < 16) stage(cur ^ 1, (t + 1) << 6);
    #pragma unroll
    for (int kk = 0; kk < 2; ++kk) {
      bf16x8 bfv = *reinterpret_cast<const bf16x8*>(&s_at[lrow * 1032 + (t << 6) + (kk << 5) + kt]);
      #pragma unroll
      for (int mi = 0; mi < 2; ++mi) {
        bf16x8 af = *reinterpret_cast<const bf16x8*>(
            &sA[cur][((w * 2 + mi) * 16 + lrow) * 64 + (kk << 5) + kt]);
        acc[mi] = __builtin_amdgcn_mfma_f32_16x16x32_bf16(af, bfv, acc[mi], 0, 0, 0);
      }
    }
    cur ^= 1;
  }

  const int rb = (lane >> 4) << 2;
  const int s = lrow;
  #pragma unroll
  for (int mi = 0; mi < 2; ++mi) {
    int e0 = (et << 7) + (w * 2 + mi) * 16 + rb;
    ushort4 o;
    o.x = f2bf(acc[mi][0]); o.y = f2bf(acc[mi][1]);
    o.z = f2bf(acc[mi][2]); o.w = f2bf(acc[mi][3]);
    *reinterpret_cast<ushort4*>(&A2[(size_t)((b_ << 4) + s) * 1024 + e0]) = o;
  }
}

// ---------------- MFMA GEMM 64x64 (slot-sized GEMMs, BK=64) ----------------

template<int BIAS, int RELU, int ADDSRC, int OUTBF16, int GATES>
__global__ __launch_bounds__(256) void gemm_sm(
    const unsigned short* __restrict__ A, const unsigned short* __restrict__ W,
    const float* __restrict__ bias, const float* __restrict__ addsrc,
    void* __restrict__ Cout, int M, int N, int K) {
  __shared__ unsigned short sA[2][4096];
  __shared__ unsigned short sB[2][4096];
  const int tid = threadIdx.x;
  const int lane = tid & 63, w = tid >> 6;

  int nwg = gridDim.x * gridDim.y;
  int flat = blockIdx.y * gridDim.x + blockIdx.x;
  if ((nwg & 7) == 0) { int c = nwg >> 3; flat = (flat & 7) * c + (flat >> 3); }
  const int row0 = (flat / gridDim.x) << 6;
  const int col0 = (flat % gridDim.x) << 6;

  int kb = 0, ke = K;
  if (GATES) {
    if (col0 >= 1536)      { kb = 512; ke = 1024; }
    else if (col0 >= 1024) { kb = 0;   ke = 512;  }
  }

  const int lrow = lane & 15, kt = (lane >> 4) << 3;
  const int sr8 = lane >> 3, sc8 = (lane & 7) << 3;

  f32x4 acc[4];
  #pragma unroll
  for (int m = 0; m < 4; ++m) acc[m] = f32x4{0.f, 0.f, 0.f, 0.f};

  auto stage = [&](int buf, int k0) {
    #pragma unroll
    for (int i = 0; i < 2; ++i) {
      int ii = (w << 1) + i;
      int r = (ii << 3) + sr8;
      GLD16(A + (size_t)(row0 + r) * K + k0 + sc8, &sA[buf][ii * 512]);
      GLD16(W + (size_t)(col0 + r) * K + k0 + sc8, &sB[buf][ii * 512]);
    }
  };

  stage(0, kb);
  const int nt = (ke - kb) >> 6;
  int cur = 0;
  for (int t = 0; t < nt; ++t) {
    __syncthreads();
    if (t + 1 < nt) stage(cur ^ 1, kb + ((t + 1) << 6));
    #pragma unroll
    for (int kk = 0; kk < 2; ++kk) {
      bf16x8 bfv = *reinterpret_cast<const bf16x8*>(
          &sB[cur][((w << 4) + lrow) * 64 + (kk << 5) + kt]);
      #pragma unroll
      for (int m = 0; m < 4; ++m) {
        bf16x8 af = *reinterpret_cast<const bf16x8*>(
            &sA[cur][(m * 16 + lrow) * 64 + (kk << 5) + kt]);
        acc[m] = __builtin_amdgcn_mfma_f32_16x16x32_bf16(af, bfv, acc[m], 0, 0, 0);
      }
    }
    cur ^= 1;
  }

  const int rb = (lane >> 4) << 2;
  const int col = col0 + (w << 4) + lrow;
  float bv = BIAS ? bias[col] : 0.0f;
  #pragma unroll
  for (int m = 0; m < 4; ++m) {
    #pragma unroll
    for (int r = 0; r < 4; ++r) {
      int row = row0 + m * 16 + rb + r;
      float v = acc[m][r] + bv;
      if (ADDSRC) v += addsrc[(size_t)row * N + col];
      if (RELU) v = fmaxf(v, 0.0f);
      if (OUTBF16) ((unsigned short*)Cout)[(size_t)row * N + col] = f2bf(v);
      else ((float*)Cout)[(size_t)row * N + col] = v;
    }
  }
}

// ---------------- host launch ----------------

extern "C" void kernel_launch(void* const* d_in, const int* in_sizes, int n_in,
                              void* d_out, int out_size, void* d_ws, size_t ws_size,
                              hipStream_t stream) {
  const float* inputs  = (const float*)d_in[0];
  const float* noise   = (const float*)d_in[1];
  const float* slot_mu = (const float*)d_in[2];
  const float* slot_ls = (const float*)d_in[3];
  const float* ln_in_g = (const float*)d_in[4];
  const float* ln_in_b = (const float*)d_in[5];
  const float* ln_s_g  = (const float*)d_in[6];
  const float* ln_s_b  = (const float*)d_in[7];
  const float* ln_m_g  = (const float*)d_in[8];
  const float* ln_m_b  = (const float*)d_in[9];
  const float* Wq   = (const float*)d_in[10];
  const float* Wk   = (const float*)d_in[11];
  const float* Wv   = (const float*)d_in[12];
  const float* w_ih = (const float*)d_in[13];
  const float* w_hh = (const float*)d_in[14];
  const float* b_ih = (const float*)d_in[15];
  const float* b_hh = (const float*)d_in[16];
  const float* w1   = (const float*)d_in[17];
  const float* b1   = (const float*)d_in[18];
  const float* w2   = (const float*)d_in[19];
  const float* b2   = (const float*)d_in[20];

  const int BN = 65536, BS = 1024;

  uintptr_t base = (uintptr_t)d_ws;
  auto alloc = [&](size_t bytes) {
    void* p = (void*)base;
    base += (bytes + 255) & ~(size_t)255;
    return p;
  };
  unsigned short* x_bf    = (unsigned short*)alloc((size_t)BN * 512 * 2);
  unsigned short* xT      = (unsigned short*)alloc((size_t)64 * 512 * 1024 * 2);
  unsigned short* wqT     = (unsigned short*)alloc(512 * 512 * 2);
  unsigned short* wkT     = (unsigned short*)alloc(512 * 512 * 2);
  unsigned short* wvT     = (unsigned short*)alloc(512 * 512 * 2);
  unsigned short* wpt     = (unsigned short*)alloc(512 * 512 * 2);
  unsigned short* wih_bf  = (unsigned short*)alloc((size_t)1536 * 512 * 2);
  unsigned short* wcat_bf = (unsigned short*)alloc((size_t)2048 * 1024 * 2);
  float*          bcat    = (float*)alloc(2048 * 4);
  unsigned short* w1_bf   = (unsigned short*)alloc(512 * 512 * 2);
  unsigned short* w2_bf   = (unsigned short*)alloc(512 * 512 * 2);
  float*          slots   = (float*)alloc((size_t)BS * 512 * 4);
  unsigned short* A2      = (unsigned short*)alloc((size_t)BS * 1024 * 2);
  unsigned short* q2_bf   = (unsigned short*)alloc((size_t)BS * 512 * 2);
  unsigned short* logits  = (unsigned short*)alloc((size_t)64 * 16 * 1024 * 2);
  float*          lstats  = (float*)alloc((size_t)64 * 16 * 8 * 2 * 4);
  float*          gates   = (float*)alloc((size_t)BS * 2048 * 4);
  float*          sgru    = (float*)alloc((size_t)BS * 512 * 4);
  unsigned short* lnm_bf  = (unsigned short*)alloc((size_t)BS * 512 * 2);
  unsigned short* h_bf    = (unsigned short*)alloc((size_t)BS * 512 * 2);
  (void)ws_size; (void)n_in; (void)in_sizes; (void)out_size;

  const float scale = 0.044194173824159216f;  // 512^-0.5

  // prologue (3 dispatches)
  wprep_k<<<13064, 256, 0, stream>>>(w1, w2, w_ih, w_hh, b_ih, b_hh,
                                     slot_mu, slot_ls, noise, Wq, Wk, Wv,
                                     w1_bf, w2_bf, wih_bf, wcat_bf, bcat, slots,
                                     wqT, wkT, wvT);
  gemm_pre<<<64, 256, 0, stream>>>(wih_bf, wvT, wkT, wqT, wcat_bf, wpt, scale);
  ln_xt_k<<<1024, 512, 0, stream>>>(inputs, ln_in_g, ln_in_b, x_bf, xT);

  for (int it = 0; it < 3; ++it) {
    q2ln_k<<<dim3(4, 64), 256, 0, stream>>>(slots, ln_s_g, ln_s_b, wpt, q2_bf, A2);
    logits_k<<<dim3(8, 64), 256, 0, stream>>>(q2_bf, x_bf, logits, lstats);
    pv_sm_k<<<dim3(4, 64), 256, 0, stream>>>(logits, lstats, xT, A2);
    gemm_sm<1,0,0,0,1><<<dim3(32, 16), 256, 0, stream>>>(
        A2, wcat_bf, bcat, nullptr, gates, BS, 2048, 1024);
    gru_ln_k<<<256, 256, 0, stream>>>(gates, slots, ln_m_g, ln_m_b, sgru, lnm_bf);
    gemm_sm<1,1,0,1,0><<<dim3(8, 16), 256, 0, stream>>>(
        lnm_bf, w1_bf, b1, nullptr, h_bf, BS, 512, 512);
    float* slots_out = (it == 2) ? (float*)d_out : slots;
    gemm_sm<1,0,1,0,0><<<dim3(8, 16), 256, 0, stream>>>(
        h_bf, w2_bf, b2, sgru, slots_out, BS, 512, 512);
  }
}

// Round 17
// 307.402 us; speedup vs baseline: 1.0187x; 1.0008x over previous
//
#include <hip/hip_runtime.h>
#include <hip/hip_bf16.h>
#include <cstdint>
#include <cstddef>

// Shapes fixed: B=64, N=1024, D=512, S=16, 3 iterations.
// Algebra: logits = sn·W'·x^T, W' = scale·Wq^T·Wk   (k never materialized)
//          ax = attn·x;  upd@Wih^T = ax@(Wih·Wv)^T  (v never materialized)
// R17: ln_xt phase-2 reads vectorized to ushort2 (32 LDS reads/thread, was 64);
//      bank pattern 2-way max (free). Bit-identical output.

typedef __bf16 bf16x8 __attribute__((ext_vector_type(8)));
typedef float f32x4 __attribute__((ext_vector_type(4)));

__device__ __forceinline__ float bf2f(unsigned int u) {
  union { unsigned int i; float f; } v; v.i = u << 16; return v.f;
}
__device__ __forceinline__ unsigned short f2bf(float x) {
  __hip_bfloat16 h = __float2bfloat16(x);
  unsigned short u;
  __builtin_memcpy(&u, &h, 2);
  return u;
}

#define GLD16(gp, lp)                                                       \
  __builtin_amdgcn_global_load_lds(                                         \
      (const __attribute__((address_space(1))) void*)(gp),                  \
      (__attribute__((address_space(3))) void*)(lp), 16, 0, 0)

// ---------------- merged prep (segmented grid, 13064 blocks) ----------------

__global__ void wprep_k(const float* __restrict__ w1, const float* __restrict__ w2,
                        const float* __restrict__ wih, const float* __restrict__ whh,
                        const float* __restrict__ bih, const float* __restrict__ bhh,
                        const float* __restrict__ mu, const float* __restrict__ ls,
                        const float* __restrict__ noise,
                        const float* __restrict__ Wq, const float* __restrict__ Wk,
                        const float* __restrict__ Wv,
                        unsigned short* __restrict__ w1_bf, unsigned short* __restrict__ w2_bf,
                        unsigned short* __restrict__ wih_bf, unsigned short* __restrict__ wcat,
                        float* __restrict__ bcat, float* __restrict__ slots,
                        unsigned short* __restrict__ wqT, unsigned short* __restrict__ wkT,
                        unsigned short* __restrict__ wvT) {
  __shared__ float tt[32][33];
  int blk = blockIdx.x, t = threadIdx.x;
  if (blk < 1024) {
    int i = blk * 256 + t; w1_bf[i] = f2bf(w1[i]);
  } else if (blk < 2048) {
    int i = (blk - 1024) * 256 + t; w2_bf[i] = f2bf(w2[i]);
  } else if (blk < 5120) {
    int i = (blk - 2048) * 256 + t; wih_bf[i] = f2bf(wih[i]);
  } else if (blk < 7168) {
    int i = (blk - 5120) * 256 + t;
    int j = i >> 9, d = i & 511;
    wcat[(size_t)j * 1024 + 512 + d] = f2bf(whh[(size_t)j * 512 + d]);
  } else if (blk < 8192) {
    int i = (blk - 7168) * 256 + t;
    int j = i >> 9, d = i & 511;
    wcat[(size_t)(1536 + j) * 1024 + 512 + d] = f2bf(whh[(size_t)(1024 + j) * 512 + d]);
  } else if (blk < 10240) {
    int i = (blk - 8192) * 256 + t;
    if (i < 262144) {
      int j = i >> 9, d = i & 511;
      wcat[(size_t)(1536 + j) * 1024 + d] = 0;
    } else {
      int k = i - 262144;
      int j = k >> 9, d = k & 511;
      wcat[(size_t)(1024 + j) * 1024 + 512 + d] = 0;
    }
  } else if (blk < 10248) {
    int j = (blk - 10240) * 256 + t;
    float v;
    if (j < 1024)      v = bih[j] + bhh[j];
    else if (j < 1536) v = bih[j];
    else               v = bhh[j - 512];
    bcat[j] = v;
  } else if (blk < 12296) {
    int i = (blk - 10248) * 256 + t;
    int d = i & 511;
    slots[i] = mu[d] + expf(ls[d]) * noise[i];
  } else {
    int blk2 = blk - 12296;              // 768 transpose blocks
    int mat = blk2 >> 8, tile = blk2 & 255;
    const float* in = mat == 0 ? Wq : (mat == 1 ? Wk : Wv);
    unsigned short* out = mat == 0 ? wqT : (mat == 1 ? wkT : wvT);
    int c0 = (tile & 15) << 5, r0 = (tile >> 4) << 5;
    int tx = t & 31, ty = t >> 5;
    #pragma unroll
    for (int i = 0; i < 4; ++i)
      tt[ty + 8 * i][tx] = in[(size_t)(r0 + ty + 8 * i) * 512 + c0 + tx];
    __syncthreads();
    #pragma unroll
    for (int i = 0; i < 4; ++i)
      out[(size_t)(c0 + ty + 8 * i) * 512 + r0 + tx] = f2bf(tt[tx][ty + 8 * i]);
  }
}

// ---------------- ln_xt: LN(inputs) -> x_bf AND xT; 64 rows/block, 512 thr ----------------
// LDS col swizzle: c ^ (((r>>3)&7)<<3). Phase 2: ushort2 reads (2 e per read),
// each thread emits two xT rows; 8-lane 128B write bursts.

__global__ __launch_bounds__(512) void ln_xt_k(
    const float* __restrict__ in, const float* __restrict__ g, const float* __restrict__ b,
    unsigned short* __restrict__ x_bf, unsigned short* __restrict__ xT) {
  __shared__ unsigned short tbuf[64 * 520];
  const int row0 = blockIdx.x << 6;
  const int bb_ = row0 >> 10;
  const int n0 = row0 & 1023;
  const int w = threadIdx.x >> 6, lane = threadIdx.x & 63;

  const float4* gp = reinterpret_cast<const float4*>(g);
  const float4* bp = reinterpret_cast<const float4*>(b);
  float4 g0 = gp[lane], g1 = gp[lane + 64];
  float4 b0 = bp[lane], b1 = bp[lane + 64];

  #pragma unroll
  for (int i = 0; i < 8; ++i) {
    int r = (w << 3) + i;
    int row = row0 + r;
    const float4* rp = reinterpret_cast<const float4*>(in + (size_t)row * 512);
    float4 v0 = rp[lane], v1 = rp[lane + 64];
    float s = v0.x + v0.y + v0.z + v0.w + v1.x + v1.y + v1.z + v1.w;
    float q = v0.x*v0.x + v0.y*v0.y + v0.z*v0.z + v0.w*v0.w
            + v1.x*v1.x + v1.y*v1.y + v1.z*v1.z + v1.w*v1.w;
    #pragma unroll
    for (int o = 32; o > 0; o >>= 1) { s += __shfl_xor(s, o); q += __shfl_xor(q, o); }
    float m = s * (1.0f / 512.0f);
    float rstd = rsqrtf(q * (1.0f / 512.0f) - m * m + 1e-8f);
    ushort4 o0, o1;
    o0.x = f2bf((v0.x - m) * rstd * g0.x + b0.x);
    o0.y = f2bf((v0.y - m) * rstd * g0.y + b0.y);
    o0.z = f2bf((v0.z - m) * rstd * g0.z + b0.z);
    o0.w = f2bf((v0.w - m) * rstd * g0.w + b0.w);
    o1.x = f2bf((v1.x - m) * rstd * g1.x + b1.x);
    o1.y = f2bf((v1.y - m) * rstd * g1.y + b1.y);
    o1.z = f2bf((v1.z - m) * rstd * g1.z + b1.z);
    o1.w = f2bf((v1.w - m) * rstd * g1.w + b1.w);
    ushort4* op = reinterpret_cast<ushort4*>(x_bf + (size_t)row * 512);
    op[lane] = o0; op[lane + 64] = o1;
    const int key = ((r >> 3) & 7) << 3;
    *reinterpret_cast<ushort4*>(&tbuf[r * 520 + ((lane * 4) ^ key)]) = o0;
    *reinterpret_cast<ushort4*>(&tbuf[r * 520 + ((256 + lane * 4) ^ key)]) = o1;
  }
  __syncthreads();

  // transpose: thread = (e-pair ep = tid>>3, n8 = (tid&7)*8); 4 passes of 128 e.
  // ushort2 read at (n, e^key) yields cols (e, e+1); 8 lanes share an e-pair
  // and cover n 0..63 -> two 128B-burst rows per pass.
  const int ep = threadIdx.x >> 3;            // 0..63
  const int n8 = (threadIdx.x & 7) << 3;      // 0..56
  const int key = ((n8 >> 3) & 7) << 3;       // constant over rows n8..n8+7
  #pragma unroll
  for (int et = 0; et < 4; ++et) {
    int e = (et << 7) + (ep << 1);
    int es = e ^ key;                          // even -> 4B-aligned
    unsigned short a0[8], a1[8];
    #pragma unroll
    for (int j = 0; j < 8; ++j) {
      unsigned int v = *reinterpret_cast<const unsigned int*>(&tbuf[(n8 + j) * 520 + es]);
      a0[j] = (unsigned short)(v & 0xffff);
      a1[j] = (unsigned short)(v >> 16);
    }
    unsigned short* o0 = xT + ((size_t)(bb_ << 9) + e) * 1024 + n0 + n8;
    unsigned short* o1 = o0 + 1024;
    *reinterpret_cast<ushort4*>(o0)     = *reinterpret_cast<ushort4*>(&a0[0]);
    *reinterpret_cast<ushort4*>(o0 + 4) = *reinterpret_cast<ushort4*>(&a0[4]);
    *reinterpret_cast<ushort4*>(o1)     = *reinterpret_cast<ushort4*>(&a1[0]);
    *reinterpret_cast<ushort4*>(o1 + 4) = *reinterpret_cast<ushort4*>(&a1[4]);
  }
}

// GRU (fused-gates layout) + LN
__global__ __launch_bounds__(256) void gru_ln_k(
    const float* __restrict__ gates, const float* __restrict__ hp,
    const float* __restrict__ g, const float* __restrict__ b,
    float* __restrict__ sgru, unsigned short* __restrict__ lnm) {
  int w = threadIdx.x >> 6, lane = threadIdx.x & 63;
  int row = (blockIdx.x << 2) + w;
  size_t gb = (size_t)row * 2048 + (lane << 3);
  size_t hb = (size_t)row * 512 + (lane << 3);
  float rs[8], zs[8], in_[8], hn[8], hv[8], y[8];
  #pragma unroll
  for (int c = 0; c < 2; ++c) {
    *reinterpret_cast<float4*>(rs + 4*c)  = *reinterpret_cast<const float4*>(gates + gb + 4*c);
    *reinterpret_cast<float4*>(zs + 4*c)  = *reinterpret_cast<const float4*>(gates + gb + 512 + 4*c);
    *reinterpret_cast<float4*>(in_ + 4*c) = *reinterpret_cast<const float4*>(gates + gb + 1024 + 4*c);
    *reinterpret_cast<float4*>(hn + 4*c)  = *reinterpret_cast<const float4*>(gates + gb + 1536 + 4*c);
    *reinterpret_cast<float4*>(hv + 4*c)  = *reinterpret_cast<const float4*>(hp + hb + 4*c);
  }
  float s = 0.f, q = 0.f;
  #pragma unroll
  for (int j = 0; j < 8; ++j) {
    float r = 1.0f / (1.0f + expf(-rs[j]));
    float z = 1.0f / (1.0f + expf(-zs[j]));
    float n = tanhf(in_[j] + r * hn[j]);
    float h = (1.0f - z) * n + z * hv[j];
    y[j] = h; s += h; q += h * h;
  }
  #pragma unroll
  for (int o = 32; o > 0; o >>= 1) { s += __shfl_xor(s, o); q += __shfl_xor(q, o); }
  float m = s * (1.0f / 512.0f);
  float rstd = rsqrtf(q * (1.0f / 512.0f) - m * m + 1e-8f);
  const float* gg = g + (lane << 3);
  const float* bb = b + (lane << 3);
  #pragma unroll
  for (int c = 0; c < 2; ++c)
    *reinterpret_cast<float4*>(sgru + hb + 4*c) = *reinterpret_cast<const float4*>(y + 4*c);
  uint4 o4;
  unsigned int p[8];
  #pragma unroll
  for (int j = 0; j < 8; ++j) p[j] = f2bf((y[j] - m) * rstd * gg[j] + bb[j]);
  o4.x = p[0] | (p[1] << 16); o4.y = p[2] | (p[3] << 16);
  o4.z = p[4] | (p[5] << 16); o4.w = p[6] | (p[7] << 16);
  *reinterpret_cast<uint4*>(lnm + hb) = o4;
}

// ---------------- gemm_pre: 64 blocks = gemm_cat(48) + W'T gemm(16), 128x128, BK=64 ----------------

__global__ __launch_bounds__(256) void gemm_pre(
    const unsigned short* __restrict__ wih_bf, const unsigned short* __restrict__ wvT,
    const unsigned short* __restrict__ wkT, const unsigned short* __restrict__ wqT,
    unsigned short* __restrict__ wcat, unsigned short* __restrict__ wpt, float scale) {
  __shared__ unsigned short sA[2][8192];
  __shared__ unsigned short sB[2][8192];
  const int blk = blockIdx.x;
  const int lane = threadIdx.x & 63, w = threadIdx.x >> 6;

  const unsigned short *A, *W;
  unsigned short* C;
  int row0, col0, ldc;
  float sc;
  if (blk < 48) {
    A = wih_bf; W = wvT; C = wcat; ldc = 1024; sc = 1.0f;
    row0 = (blk >> 2) << 7; col0 = (blk & 3) << 7;
  } else {
    A = wkT; W = wqT; C = wpt; ldc = 512; sc = scale;
    int f = blk - 48;
    row0 = (f >> 2) << 7; col0 = (f & 3) << 7;
  }
  const int K = 512;

  const int wm = (w >> 1) << 6, wn = (w & 1) << 6;
  const int lrow = lane & 15, kt = (lane >> 4) << 3;
  const int sr8 = lane >> 3, sc8 = (lane & 7) << 3;

  f32x4 acc[4][4];
  #pragma unroll
  for (int m = 0; m < 4; ++m)
    #pragma unroll
    for (int n = 0; n < 4; ++n) acc[m][n] = f32x4{0.f, 0.f, 0.f, 0.f};

  auto stage = [&](int buf, int k0) {
    #pragma unroll
    for (int i = 0; i < 4; ++i) {
      int ii = (w << 2) + i;
      int r = (ii << 3) + sr8;
      GLD16(A + (size_t)(row0 + r) * K + k0 + sc8, &sA[buf][ii * 512]);
      GLD16(W + (size_t)(col0 + r) * K + k0 + sc8, &sB[buf][ii * 512]);
    }
  };

  stage(0, 0);
  int cur = 0;
  for (int t = 0; t < 8; ++t) {
    __syncthreads();
    if (t + 1 < 8) stage(cur ^ 1, (t + 1) << 6);
    #pragma unroll
    for (int kk = 0; kk < 2; ++kk) {
      bf16x8 af[4], bfv[4];
      #pragma unroll
      for (int m = 0; m < 4; ++m)
        af[m] = *reinterpret_cast<const bf16x8*>(&sA[cur][(wm + m * 16 + lrow) * 64 + (kk << 5) + kt]);
      #pragma unroll
      for (int n = 0; n < 4; ++n)
        bfv[n] = *reinterpret_cast<const bf16x8*>(&sB[cur][(wn + n * 16 + lrow) * 64 + (kk << 5) + kt]);
      #pragma unroll
      for (int m = 0; m < 4; ++m)
        #pragma unroll
        for (int n = 0; n < 4; ++n)
          acc[m][n] = __builtin_amdgcn_mfma_f32_16x16x32_bf16(af[m], bfv[n], acc[m][n], 0, 0, 0);
    }
    cur ^= 1;
  }

  const int rb = (lane >> 4) << 2;
  #pragma unroll
  for (int m = 0; m < 4; ++m) {
    #pragma unroll
    for (int n = 0; n < 4; ++n) {
      int col = col0 + wn + n * 16 + lrow;
      #pragma unroll
      for (int r = 0; r < 4; ++r) {
        int row = row0 + wm + m * 16 + rb + r;
        C[(size_t)row * ldc + col] = f2bf(acc[m][n][r] * sc);
      }
    }
  }
}

// ---------------- q2ln: LN(slots_b) in LDS, then q2 = sn @ W' tile (BK=64) ----------------

__global__ __launch_bounds__(256) void q2ln_k(
    const float* __restrict__ slots, const float* __restrict__ g, const float* __restrict__ b,
    const unsigned short* __restrict__ wpt, unsigned short* __restrict__ q2,
    unsigned short* __restrict__ A2) {
  __shared__ unsigned short s_sn[16 * 520];
  __shared__ unsigned short sB[2][8192];
  const int b_ = blockIdx.y, ct = blockIdx.x;
  const int lane = threadIdx.x & 63, w = threadIdx.x >> 6;
  const int lrow = lane & 15, kt = (lane >> 4) << 3;
  const int sr8 = lane >> 3, sc8 = (lane & 7) << 3;

  const float4* gp = reinterpret_cast<const float4*>(g);
  const float4* bp = reinterpret_cast<const float4*>(b);
  float4 g0 = gp[lane], g1 = gp[lane + 64];
  float4 b0 = bp[lane], b1 = bp[lane + 64];
  #pragma unroll
  for (int rr = 0; rr < 4; ++rr) {
    int r = w * 4 + rr;
    const float4* rp = reinterpret_cast<const float4*>(slots + (size_t)(b_ * 16 + r) * 512);
    float4 v0 = rp[lane], v1 = rp[lane + 64];
    float s = v0.x + v0.y + v0.z + v0.w + v1.x + v1.y + v1.z + v1.w;
    float q = v0.x*v0.x + v0.y*v0.y + v0.z*v0.z + v0.w*v0.w
            + v1.x*v1.x + v1.y*v1.y + v1.z*v1.z + v1.w*v1.w;
    #pragma unroll
    for (int o = 32; o > 0; o >>= 1) { s += __shfl_xor(s, o); q += __shfl_xor(q, o); }
    float m = s * (1.0f / 512.0f);
    float rstd = rsqrtf(q * (1.0f / 512.0f) - m * m + 1e-8f);
    ushort4 o0, o1;
    o0.x = f2bf((v0.x - m) * rstd * g0.x + b0.x);
    o0.y = f2bf((v0.y - m) * rstd * g0.y + b0.y);
    o0.z = f2bf((v0.z - m) * rstd * g0.z + b0.z);
    o0.w = f2bf((v0.w - m) * rstd * g0.w + b0.w);
    o1.x = f2bf((v1.x - m) * rstd * g1.x + b1.x);
    o1.y = f2bf((v1.y - m) * rstd * g1.y + b1.y);
    o1.z = f2bf((v1.z - m) * rstd * g1.z + b1.z);
    o1.w = f2bf((v1.w - m) * rstd * g1.w + b1.w);
    *reinterpret_cast<ushort4*>(&s_sn[r * 520 + lane * 4]) = o0;
    *reinterpret_cast<ushort4*>(&s_sn[r * 520 + 256 + lane * 4]) = o1;
    if (ct == 0) {
      ushort4 c0, c1;
      c0.x = f2bf(v0.x); c0.y = f2bf(v0.y); c0.z = f2bf(v0.z); c0.w = f2bf(v0.w);
      c1.x = f2bf(v1.x); c1.y = f2bf(v1.y); c1.z = f2bf(v1.z); c1.w = f2bf(v1.w);
      unsigned short* a2r = A2 + (size_t)(b_ * 16 + r) * 1024 + 512;
      *reinterpret_cast<ushort4*>(a2r + lane * 4) = c0;
      *reinterpret_cast<ushort4*>(a2r + 256 + lane * 4) = c1;
    }
  }

  const unsigned short* Bb = wpt + (size_t)(ct << 7) * 512;
  auto stage = [&](int buf, int k0) {
    #pragma unroll
    for (int i = 0; i < 4; ++i) {
      int ii = (w << 2) + i;
      GLD16(Bb + (size_t)((ii << 3) + sr8) * 512 + k0 + sc8, &sB[buf][ii * 512]);
    }
  };

  f32x4 acc[2];
  acc[0] = f32x4{0.f, 0.f, 0.f, 0.f};
  acc[1] = f32x4{0.f, 0.f, 0.f, 0.f};

  stage(0, 0);
  int cur = 0;
  for (int t = 0; t < 8; ++t) {
    __syncthreads();
    if (t + 1 < 8) stage(cur ^ 1, (t + 1) << 6);
    #pragma unroll
    for (int kk = 0; kk < 2; ++kk) {
      bf16x8 af = *reinterpret_cast<const bf16x8*>(&s_sn[lrow * 520 + (t << 6) + (kk << 5) + kt]);
      #pragma unroll
      for (int ni = 0; ni < 2; ++ni) {
        bf16x8 bfv = *reinterpret_cast<const bf16x8*>(
            &sB[cur][((w * 2 + ni) * 16 + lrow) * 64 + (kk << 5) + kt]);
        acc[ni] = __builtin_amdgcn_mfma_f32_16x16x32_bf16(af, bfv, acc[ni], 0, 0, 0);
      }
    }
    cur ^= 1;
  }

  const int rb = (lane >> 4) << 2;
  #pragma unroll
  for (int ni = 0; ni < 2; ++ni) {
    int col = (ct << 7) + (w * 2 + ni) * 16 + lrow;
    #pragma unroll
    for (int r = 0; r < 4; ++r) {
      int s = rb + r;
      q2[(size_t)((b_ << 4) + s) * 512 + col] = f2bf(acc[ni][r]);
    }
  }
}

// ---------------- logits + per-chunk softmax stats (bf16 out, BK=64) ----------------

__global__ __launch_bounds__(256) void logits_k(
    const unsigned short* __restrict__ q2, const unsigned short* __restrict__ x,
    unsigned short* __restrict__ out, float* __restrict__ lstats) {
  __shared__ unsigned short sA[2][1024];
  __shared__ unsigned short sB[2][8192];
  __shared__ float sstat[16][4][2];
  const int b = blockIdx.y, nt = blockIdx.x;
  const int lane = threadIdx.x & 63, w = threadIdx.x >> 6;
  const int lrow = lane & 15, kt = (lane >> 4) << 3;
  const int sr8 = lane >> 3, sc8 = (lane & 7) << 3;
  const unsigned short* Ab = q2 + ((size_t)b << 13);
  const unsigned short* Bb = x + (((size_t)(b << 10) + (nt << 7)) << 9);

  f32x4 acc[2];
  acc[0] = f32x4{0.f, 0.f, 0.f, 0.f};
  acc[1] = f32x4{0.f, 0.f, 0.f, 0.f};

  auto stage = [&](int buf, int k0) {
    #pragma unroll
    for (int i = 0; i < 4; ++i) {
      int ii = (w << 2) + i;
      GLD16(Bb + (size_t)((ii << 3) + sr8) * 512 + k0 + sc8, &sB[buf][ii * 512]);
    }
    if (w == 0) {
      #pragma unroll
      for (int i = 0; i < 2; ++i)
        GLD16(Ab + (size_t)((i << 3) + sr8) * 512 + k0 + sc8, &sA[buf][i * 512]);
    }
  };

  stage(0, 0);
  int cur = 0;
  for (int t = 0; t < 8; ++t) {
    __syncthreads();
    if (t + 1 < 8) stage(cur ^ 1, (t + 1) << 6);
    #pragma unroll
    for (int kk = 0; kk < 2; ++kk) {
      bf16x8 af = *reinterpret_cast<const bf16x8*>(&sA[cur][lrow * 64 + (kk << 5) + kt]);
      #pragma unroll
      for (int ni = 0; ni < 2; ++ni) {
        bf16x8 bfv = *reinterpret_cast<const bf16x8*>(
            &sB[cur][((w * 2 + ni) * 16 + lrow) * 64 + (kk << 5) + kt]);
        acc[ni] = __builtin_amdgcn_mfma_f32_16x16x32_bf16(af, bfv, acc[ni], 0, 0, 0);
      }
    }
    cur ^= 1;
  }

  const int rb = (lane >> 4) << 2;
  unsigned short lv[2][4];
  #pragma unroll
  for (int ni = 0; ni < 2; ++ni) {
    int n = (nt << 7) + (w * 2 + ni) * 16 + lrow;
    #pragma unroll
    for (int r = 0; r < 4; ++r) {
      unsigned short u = f2bf(acc[ni][r]);
      lv[ni][r] = u;
      out[(size_t)((b << 4) + rb + r) * 1024 + n] = u;
    }
  }
  #pragma unroll
  for (int r = 0; r < 4; ++r) {
    float v0 = bf2f(lv[0][r]), v1 = bf2f(lv[1][r]);
    float m = fmaxf(v0, v1);
    #pragma unroll
    for (int o = 1; o < 16; o <<= 1) m = fmaxf(m, __shfl_xor(m, o));
    float l = __expf(v0 - m) + __expf(v1 - m);
    #pragma unroll
    for (int o = 1; o < 16; o <<= 1) l += __shfl_xor(l, o);
    if (lrow == 0) { sstat[rb + r][w][0] = m; sstat[rb + r][w][1] = l; }
  }
  __syncthreads();
  if (threadIdx.x < 16) {
    int s = threadIdx.x;
    float m = sstat[s][0][0];
    #pragma unroll
    for (int c = 1; c < 4; ++c) m = fmaxf(m, sstat[s][c][0]);
    float l = 0.f;
    #pragma unroll
    for (int c = 0; c < 4; ++c) l += sstat[s][c][1] * __expf(sstat[s][c][0] - m);
    float* lp = lstats + (((size_t)(b << 4) + s) * 8 + nt) * 2;
    lp[0] = m; lp[1] = l;
  }
}

// ---------------- pv_sm: stats-combine + colnorm (LDS attn) + ax MFMA vs xT ----------------

__global__ __launch_bounds__(256) void pv_sm_k(
    const unsigned short* __restrict__ logits, const float* __restrict__ lstats,
    const unsigned short* __restrict__ xT, unsigned short* __restrict__ A2) {
  __shared__ float s_mi[16][2];
  __shared__ unsigned short s_at[16 * 1032];
  __shared__ unsigned short sA[2][8192];
  const int b_ = blockIdx.y, et = blockIdx.x;
  const int lane = threadIdx.x & 63, w = threadIdx.x >> 6;
  const int lrow = lane & 15, kt = (lane >> 4) << 3;
  const int sr8 = lane >> 3, sc8 = (lane & 7) << 3;
  const unsigned short* lg = logits + ((size_t)b_ << 14);

  if (threadIdx.x < 16) {
    int s = threadIdx.x;
    const float* lp = lstats + (((size_t)(b_ << 4) + s) * 8) * 2;
    float m = lp[0];
    #pragma unroll
    for (int c = 1; c < 8; ++c) m = fmaxf(m, lp[c * 2]);
    float l = 0.f;
    #pragma unroll
    for (int c = 0; c < 8; ++c) l += lp[c * 2 + 1] * __expf(lp[c * 2] - m);
    s_mi[s][0] = m; s_mi[s][1] = 1.0f / l;
  }
  __syncthreads();

  #pragma unroll
  for (int j = 0; j < 4; ++j) {
    int c = threadIdx.x + (j << 8);
    float e[16];
    float cs = 0.f;
    #pragma unroll
    for (int s = 0; s < 16; ++s) {
      e[s] = __expf(bf2f(lg[(size_t)s * 1024 + c]) - s_mi[s][0]) * s_mi[s][1];
      cs += e[s];
    }
    float rv = 1.0f / (cs + 1e-8f);
    #pragma unroll
    for (int s = 0; s < 16; ++s) s_at[s * 1032 + c] = f2bf(e[s] * rv);
  }

  const unsigned short* Ab = xT + ((size_t)b_ << 19) + (size_t)(et << 7) * 1024;
  auto stage = [&](int buf, int k0) {
    #pragma unroll
    for (int i = 0; i < 4; ++i) {
      int ii = (w << 2) + i;
      GLD16(Ab + (size_t)((ii << 3) + sr8) * 1024 + k0 + sc8, &sA[buf][ii * 512]);
    }
  };

  f32x4 acc[2];
  acc[0] = f32x4{0.f, 0.f, 0.f, 0.f};
  acc[1] = f32x4{0.f, 0.f, 0.f, 0.f};

  stage(0, 0);
  int cur = 0;
  for (int t = 0; t < 16; ++t) {
    __syncthreads();
    if (t + 1 < 16) stage(cur ^ 1, (t + 1) << 6);
    #pragma unroll
    for (int kk = 0; kk < 2; ++kk) {
      bf16x8 bfv = *reinterpret_cast<const bf16x8*>(&s_at[lrow * 1032 + (t << 6) + (kk << 5) + kt]);
      #pragma unroll
      for (int mi = 0; mi < 2; ++mi) {
        bf16x8 af = *reinterpret_cast<const bf16x8*>(
            &sA[cur][((w * 2 + mi) * 16 + lrow) * 64 + (kk << 5) + kt]);
        acc[mi] = __builtin_amdgcn_mfma_f32_16x16x32_bf16(af, bfv, acc[mi], 0, 0, 0);
      }
    }
    cur ^= 1;
  }

  const int rb = (lane >> 4) << 2;
  const int s = lrow;
  #pragma unroll
  for (int mi = 0; mi < 2; ++mi) {
    int e0 = (et << 7) + (w * 2 + mi) * 16 + rb;
    ushort4 o;
    o.x = f2bf(acc[mi][0]); o.y = f2bf(acc[mi][1]);
    o.z = f2bf(acc[mi][2]); o.w = f2bf(acc[mi][3]);
    *reinterpret_cast<ushort4*>(&A2[(size_t)((b_ << 4) + s) * 1024 + e0]) = o;
  }
}

// ---------------- MFMA GEMM 64x64 (slot-sized GEMMs, BK=64) ----------------

template<int BIAS, int RELU, int ADDSRC, int OUTBF16, int GATES>
__global__ __launch_bounds__(256) void gemm_sm(
    const unsigned short* __restrict__ A, const unsigned short* __restrict__ W,
    const float* __restrict__ bias, const float* __restrict__ addsrc,
    void* __restrict__ Cout, int M, int N, int K) {
  __shared__ unsigned short sA[2][4096];
  __shared__ unsigned short sB[2][4096];
  const int tid = threadIdx.x;
  const int lane = tid & 63, w = tid >> 6;

  int nwg = gridDim.x * gridDim.y;
  int flat = blockIdx.y * gridDim.x + blockIdx.x;
  if ((nwg & 7) == 0) { int c = nwg >> 3; flat = (flat & 7) * c + (flat >> 3); }
  const int row0 = (flat / gridDim.x) << 6;
  const int col0 = (flat % gridDim.x) << 6;

  int kb = 0, ke = K;
  if (GATES) {
    if (col0 >= 1536)      { kb = 512; ke = 1024; }
    else if (col0 >= 1024) { kb = 0;   ke = 512;  }
  }

  const int lrow = lane & 15, kt = (lane >> 4) << 3;
  const int sr8 = lane >> 3, sc8 = (lane & 7) << 3;

  f32x4 acc[4];
  #pragma unroll
  for (int m = 0; m < 4; ++m) acc[m] = f32x4{0.f, 0.f, 0.f, 0.f};

  auto stage = [&](int buf, int k0) {
    #pragma unroll
    for (int i = 0; i < 2; ++i) {
      int ii = (w << 1) + i;
      int r = (ii << 3) + sr8;
      GLD16(A + (size_t)(row0 + r) * K + k0 + sc8, &sA[buf][ii * 512]);
      GLD16(W + (size_t)(col0 + r) * K + k0 + sc8, &sB[buf][ii * 512]);
    }
  };

  stage(0, kb);
  const int nt = (ke - kb) >> 6;
  int cur = 0;
  for (int t = 0; t < nt; ++t) {
    __syncthreads();
    if (t + 1 < nt) stage(cur ^ 1, kb + ((t + 1) << 6));
    #pragma unroll
    for (int kk = 0; kk < 2; ++kk) {
      bf16x8 bfv = *reinterpret_cast<const bf16x8*>(
          &sB[cur][((w << 4) + lrow) * 64 + (kk << 5) + kt]);
      #pragma unroll
      for (int m = 0; m < 4; ++m) {
        bf16x8 af = *reinterpret_cast<const bf16x8*>(
            &sA[cur][(m * 16 + lrow) * 64 + (kk << 5) + kt]);
        acc[m] = __builtin_amdgcn_mfma_f32_16x16x32_bf16(af, bfv, acc[m], 0, 0, 0);
      }
    }
    cur ^= 1;
  }

  const int rb = (lane >> 4) << 2;
  const int col = col0 + (w << 4) + lrow;
  float bv = BIAS ? bias[col] : 0.0f;
  #pragma unroll
  for (int m = 0; m < 4; ++m) {
    #pragma unroll
    for (int r = 0; r < 4; ++r) {
      int row = row0 + m * 16 + rb + r;
      float v = acc[m][r] + bv;
      if (ADDSRC) v += addsrc[(size_t)row * N + col];
      if (RELU) v = fmaxf(v, 0.0f);
      if (OUTBF16) ((unsigned short*)Cout)[(size_t)row * N + col] = f2bf(v);
      else ((float*)Cout)[(size_t)row * N + col] = v;
    }
  }
}

// ---------------- host launch ----------------

extern "C" void kernel_launch(void* const* d_in, const int* in_sizes, int n_in,
                              void* d_out, int out_size, void* d_ws, size_t ws_size,
                              hipStream_t stream) {
  const float* inputs  = (const float*)d_in[0];
  const float* noise   = (const float*)d_in[1];
  const float* slot_mu = (const float*)d_in[2];
  const float* slot_ls = (const float*)d_in[3];
  const float* ln_in_g = (const float*)d_in[4];
  const float* ln_in_b = (const float*)d_in[5];
  const float* ln_s_g  = (const float*)d_in[6];
  const float* ln_s_b  = (const float*)d_in[7];
  const float* ln_m_g  = (const float*)d_in[8];
  const float* ln_m_b  = (const float*)d_in[9];
  const float* Wq   = (const float*)d_in[10];
  const float* Wk   = (const float*)d_in[11];
  const float* Wv   = (const float*)d_in[12];
  const float* w_ih = (const float*)d_in[13];
  const float* w_hh = (const float*)d_in[14];
  const float* b_ih = (const float*)d_in[15];
  const float* b_hh = (const float*)d_in[16];
  const float* w1   = (const float*)d_in[17];
  const float* b1   = (const float*)d_in[18];
  const float* w2   = (const float*)d_in[19];
  const float* b2   = (const float*)d_in[20];

  const int BN = 65536, BS = 1024;

  uintptr_t base = (uintptr_t)d_ws;
  auto alloc = [&](size_t bytes) {
    void* p = (void*)base;
    base += (bytes + 255) & ~(size_t)255;
    return p;
  };
  unsigned short* x_bf    = (unsigned short*)alloc((size_t)BN * 512 * 2);
  unsigned short* xT      = (unsigned short*)alloc((size_t)64 * 512 * 1024 * 2);
  unsigned short* wqT     = (unsigned short*)alloc(512 * 512 * 2);
  unsigned short* wkT     = (unsigned short*)alloc(512 * 512 * 2);
  unsigned short* wvT     = (unsigned short*)alloc(512 * 512 * 2);
  unsigned short* wpt     = (unsigned short*)alloc(512 * 512 * 2);
  unsigned short* wih_bf  = (unsigned short*)alloc((size_t)1536 * 512 * 2);
  unsigned short* wcat_bf = (unsigned short*)alloc((size_t)2048 * 1024 * 2);
  float*          bcat    = (float*)alloc(2048 * 4);
  unsigned short* w1_bf   = (unsigned short*)alloc(512 * 512 * 2);
  unsigned short* w2_bf   = (unsigned short*)alloc(512 * 512 * 2);
  float*          slots   = (float*)alloc((size_t)BS * 512 * 4);
  unsigned short* A2      = (unsigned short*)alloc((size_t)BS * 1024 * 2);
  unsigned short* q2_bf   = (unsigned short*)alloc((size_t)BS * 512 * 2);
  unsigned short* logits  = (unsigned short*)alloc((size_t)64 * 16 * 1024 * 2);
  float*          lstats  = (float*)alloc((size_t)64 * 16 * 8 * 2 * 4);
  float*          gates   = (float*)alloc((size_t)BS * 2048 * 4);
  float*          sgru    = (float*)alloc((size_t)BS * 512 * 4);
  unsigned short* lnm_bf  = (unsigned short*)alloc((size_t)BS * 512 * 2);
  unsigned short* h_bf    = (unsigned short*)alloc((size_t)BS * 512 * 2);
  (void)ws_size; (void)n_in; (void)in_sizes; (void)out_size;

  const float scale = 0.044194173824159216f;  // 512^-0.5

  // prologue (3 dispatches)
  wprep_k<<<13064, 256, 0, stream>>>(w1, w2, w_ih, w_hh, b_ih, b_hh,
                                     slot_mu, slot_ls, noise, Wq, Wk, Wv,
                                     w1_bf, w2_bf, wih_bf, wcat_bf, bcat, slots,
                                     wqT, wkT, wvT);
  gemm_pre<<<64, 256, 0, stream>>>(wih_bf, wvT, wkT, wqT, wcat_bf, wpt, scale);
  ln_xt_k<<<1024, 512, 0, stream>>>(inputs, ln_in_g, ln_in_b, x_bf, xT);

  for (int it = 0; it < 3; ++it) {
    q2ln_k<<<dim3(4, 64), 256, 0, stream>>>(slots, ln_s_g, ln_s_b, wpt, q2_bf, A2);
    logits_k<<<dim3(8, 64), 256, 0, stream>>>(q2_bf, x_bf, logits, lstats);
    pv_sm_k<<<dim3(4, 64), 256, 0, stream>>>(logits, lstats, xT, A2);
    gemm_sm<1,0,0,0,1><<<dim3(32, 16), 256, 0, stream>>>(
        A2, wcat_bf, bcat, nullptr, gates, BS, 2048, 1024);
    gru_ln_k<<<256, 256, 0, stream>>>(gates, slots, ln_m_g, ln_m_b, sgru, lnm_bf);
    gemm_sm<1,1,0,1,0><<<dim3(8, 16), 256, 0, stream>>>(
        lnm_bf, w1_bf, b1, nullptr, h_bf, BS, 512, 512);
    float* slots_out = (it == 2) ? (float*)d_out : slots;
    gemm_sm<1,0,1,0,0><<<dim3(8, 16), 256, 0, stream>>>(
        h_bf, w2_bf, b2, sgru, slots_out, BS, 512, 512);
  }
}